// Round 7
// baseline (159.741 us; speedup 1.0000x reference)
//
#include <hip/hip_runtime.h>
#include <hip/hip_bf16.h>
#include <math.h>

#define NSP 4096      // h*w*z = 16^3
#define CD 128        // channels
#define NB 2          // batch
#define NH 4          // heads
#define JS 4          // j-splits in attention
#define JSTEP 64
#define NSTEP ((NSP / JS) / JSTEP)   // 16

typedef __attribute__((ext_vector_type(8))) short bf16x8;   // 8 bf16 (4 VGPRs)
typedef __attribute__((ext_vector_type(4))) float f32x4;

static constexpr float QSCALE = 10.0f * 1.4426950408889634f;  // scale * log2(e)

__device__ __forceinline__ ushort f2bf(float f) {
    union { float f; unsigned u; } v; v.f = f;
    unsigned r = v.u + 0x7fffu + ((v.u >> 16) & 1u);   // RNE, finite inputs only
    return (ushort)(r >> 16);
}

// RNE pack via compiler-known builtin (emits v_cvt_pk_bf16_f32): low16=a, high16=b
__device__ __forceinline__ unsigned pk2bf(float a, float b) {
    union { __hip_bfloat162 h; unsigned u; } t;
    t.h = __float22bfloat162_rn(make_float2(a, b));
    return t.u;
}

__device__ __forceinline__ void gload_lds16(const void* g, void* l) {
    __builtin_amdgcn_global_load_lds(
        (const __attribute__((address_space(1))) unsigned int*)g,
        (__attribute__((address_space(3))) unsigned int*)l, 16, 0, 0);
}

// ---------------- fused q,k,v projection (4 n per thread, float4 loads) ----------------
// grid (NSP/1024, CD/4, NB), block 256.
__global__ __launch_bounds__(256) void proj_qkv(
    const float* __restrict__ x, const float* __restrict__ cx,
    const float* __restrict__ Wq, const float* __restrict__ Bq, float* __restrict__ qb,
    const float* __restrict__ Wk, const float* __restrict__ Bk, float* __restrict__ kb,
    const float* __restrict__ Wv, const float* __restrict__ Bv, ushort* __restrict__ V16)
{
    const int n0 = (blockIdx.x * 256 + threadIdx.x) * 4;
    const int o0 = blockIdx.y * 4;
    const int b  = blockIdx.z;
    const float* Xb = x  + (size_t)b * CD * NSP + n0;
    const float* Cb = cx + (size_t)b * CD * NSP + n0;
    f32x4 aq[4], ak[4], av[4];
    #pragma unroll
    for (int r = 0; r < 4; ++r) {
        const float bqv = Bq[o0+r], bkv = Bk[o0+r], bvv = Bv[o0+r];
        aq[r] = (f32x4){bqv, bqv, bqv, bqv};
        ak[r] = (f32x4){bkv, bkv, bkv, bkv};
        av[r] = (f32x4){bvv, bvv, bvv, bvv};
    }
    #pragma unroll 2
    for (int c = 0; c < CD; ++c) {
        const f32x4 xv = *(const f32x4*)(Xb + (size_t)c * NSP);
        const f32x4 cv = *(const f32x4*)(Cb + (size_t)c * NSP);
        #pragma unroll
        for (int r = 0; r < 4; ++r) {
            aq[r] += xv * Wq[(o0 + r) * CD + c];
            ak[r] += cv * Wk[(o0 + r) * CD + c];
            av[r] += cv * Wv[(o0 + r) * CD + c];
        }
    }
    #pragma unroll
    for (int r = 0; r < 4; ++r) {
        const size_t row = (size_t)b * CD + o0 + r;
        *(f32x4*)(qb + row * NSP + n0) = aq[r];
        *(f32x4*)(kb + row * NSP + n0) = ak[r];
        ushort4 vv;
        vv.x = f2bf(av[r].x); vv.y = f2bf(av[r].y);
        vv.z = f2bf(av[r].z); vv.w = f2bf(av[r].w);
        *(ushort4*)(V16 + row * NSP + n0) = vv;
    }
}

// ---------------- output projection (4 n per thread) ----------------
__global__ __launch_bounds__(256) void proj_one(
    const float* __restrict__ X, const float* __restrict__ W,
    const float* __restrict__ Bi, float* __restrict__ O)
{
    const int n0 = (blockIdx.x * 256 + threadIdx.x) * 4;
    const int o0 = blockIdx.y * 4;
    const int b  = blockIdx.z;
    const float* Xb = X + (size_t)b * CD * NSP + n0;
    f32x4 a[4];
    #pragma unroll
    for (int r = 0; r < 4; ++r) {
        const float bv = Bi[o0 + r];
        a[r] = (f32x4){bv, bv, bv, bv};
    }
    #pragma unroll 2
    for (int c = 0; c < CD; ++c) {
        const f32x4 xv = *(const f32x4*)(Xb + (size_t)c * NSP);
        #pragma unroll
        for (int r = 0; r < 4; ++r) a[r] += xv * W[(o0 + r) * CD + c];
    }
    #pragma unroll
    for (int r = 0; r < 4; ++r)
        *(f32x4*)(O + ((size_t)b * CD + o0 + r) * NSP + n0) = a[r];
}

// ---------------- per-(b,c)-row L2 norm scales over spatial N ----------------
__global__ __launch_bounds__(256) void rownorm(
    const float* __restrict__ qb, const float* __restrict__ kb,
    float* __restrict__ scq, float* __restrict__ sck)
{
    const int c = blockIdx.x, b = blockIdx.y, which = blockIdx.z;
    const float* row = (which ? kb : qb) + ((size_t)b * CD + c) * NSP;
    const int t = threadIdx.x;
    float ss = 0.f;
    for (int i = t * 4; i < NSP; i += 1024) {
        float4 v = *(const float4*)&row[i];
        ss = fmaf(v.x, v.x, fmaf(v.y, v.y, fmaf(v.z, v.z, fmaf(v.w, v.w, ss))));
    }
    #pragma unroll
    for (int off = 32; off > 0; off >>= 1) ss += __shfl_down(ss, off, 64);
    __shared__ float red[4];
    if ((t & 63) == 0) red[t >> 6] = ss;
    __syncthreads();
    if (t == 0) {
        const float total = red[0] + red[1] + red[2] + red[3];
        const float sc = (which ? 1.0f : QSCALE) / fmaxf(sqrtf(total), 1e-12f);
        (which ? sck : scq)[b * CD + c] = sc;
    }
}

// ---------------- pack q,k -> bf16 chunk-major [bh][n/64][c=d/8][n%64][8] ----------------
__global__ __launch_bounds__(256) void pack_qk(
    const float* __restrict__ qb, const float* __restrict__ kb,
    const float* __restrict__ scq, const float* __restrict__ sck,
    ushort* __restrict__ Qt, ushort* __restrict__ Kt)
{
    const int n  = blockIdx.x * 256 + threadIdx.x;
    const int bh = blockIdx.y;
    const int b = bh >> 2, h = bh & 3;
    unsigned qw[16], kw[16];
    #pragma unroll
    for (int dp = 0; dp < 16; ++dp) {
        const int gr = b * CD + h * 32 + 2 * dp;
        const float fq0 = qb[(size_t)gr * NSP + n] * scq[gr];
        const float fq1 = qb[(size_t)(gr + 1) * NSP + n] * scq[gr + 1];
        const float fk0 = kb[(size_t)gr * NSP + n] * sck[gr];
        const float fk1 = kb[(size_t)(gr + 1) * NSP + n] * sck[gr + 1];
        qw[dp] = pk2bf(fq0, fq1);
        kw[dp] = pk2bf(fk0, fk1);
    }
    const int jb = n >> 6, jr = n & 63;
    const size_t base = ((size_t)(bh * (NSP / 64) + jb)) * 4;
    #pragma unroll
    for (int c = 0; c < 4; ++c) {
        *(uint4*)(Qt + (base + c) * 512 + jr * 8) =
            make_uint4(qw[4*c], qw[4*c+1], qw[4*c+2], qw[4*c+3]);
        *(uint4*)(Kt + (base + c) * 512 + jr * 8) =
            make_uint4(kw[4*c], kw[4*c+1], kw[4*c+2], kw[4*c+3]);
    }
}

// ---------------- MFMA flash attention partials (LDS-staged K/V) ----------------
// 1-D grid 1024 blocks, 256 threads (4 waves). bh=f&7, i-tile=(f>>3)&31, js=f>>8.
__global__ __launch_bounds__(256, 4) void attn_mfma(
    const ushort* __restrict__ Qt, const ushort* __restrict__ Kt,
    const ushort* __restrict__ V16,
    float* __restrict__ pacc, float* __restrict__ pl)
{
    __shared__ __align__(16) ushort Kl[2][2048];   // [c=d/8][64 j][8]  (4KB each)
    __shared__ __align__(16) ushort Vl[2][2048];   // [d][8 chunks^swz][8] (4KB each)

    const int t = threadIdx.x;
    const int wid = t >> 6, lane = t & 63;
    const int g = lane >> 4, n16 = lane & 15;
    const int f = blockIdx.x;
    const int bh = f & 7, it32 = (f >> 3) & 31, js = f >> 8;
    const int b = bh >> 2, h = bh & 3;
    const int i0 = it32 * 128 + wid * 32;

    const ushort* QtB = Qt + (size_t)bh * NSP * 32;
    const ushort* KtB = Kt + (size_t)bh * NSP * 32;
    const ushort* Vb  = V16 + (size_t)(b * CD + h * 32) * NSP;

    const size_t qoff = ((size_t)(i0 >> 6) * 4 + g) * 512 + (size_t)(i0 & 32) * 8;
    const bf16x8 qf0 = *(const bf16x8*)(QtB + qoff + n16 * 8);
    const bf16x8 qf1 = *(const bf16x8*)(QtB + qoff + (16 + n16) * 8);

    f32x4 acc00 = {0,0,0,0}, acc01 = {0,0,0,0}, acc10 = {0,0,0,0}, acc11 = {0,0,0,0};
    float l0 = 0.f, l1 = 0.f;
    const f32x4 zero = {0,0,0,0};

    const bool pp      = (g & 1);
    const bool lowdest = (g < 2);
    const int srcA4 = ((32 * (g & 1)) + n16) * 4;
    const int srcB4 = srcA4 + 64;
    const int aP = lowdest ? srcA4 : srcB4;
    const int aQ = lowdest ? srcB4 : srcA4;

    const int vd  = wid * 8 + (lane >> 3);
    const int vsw = (lane & 7) ^ (lane >> 3);
    auto stageK = [&](int buf, int jt) {
        const ushort* gsrc = KtB + ((size_t)(jt >> 6) * 4 + wid) * 512 + lane * 8;
        gload_lds16(gsrc, &Kl[buf][wid * 512]);
    };
    auto stageV = [&](int buf, int jt) {
        const ushort* gsrc = Vb + (size_t)vd * NSP + jt + vsw * 8;
        gload_lds16(gsrc, &Vl[buf][wid * 512]);
    };

    const int jbeg = js * (NSP / JS);

    stageK(0, jbeg); stageV(0, jbeg);
    __syncthreads();

    int cur = 0;
    for (int step = 0; step < NSTEP; ++step) {
        const int jt = jbeg + step * JSTEP;
        if (step + 1 < NSTEP) { stageK(cur ^ 1, jt + JSTEP); stageV(cur ^ 1, jt + JSTEP); }

        #pragma unroll
        for (int s = 0; s < 2; ++s) {
            const bf16x8 kf0 = *(const bf16x8*)(&Kl[cur][g * 512 + (s * 32 + n16) * 8]);
            const bf16x8 kf1 = *(const bf16x8*)(&Kl[cur][g * 512 + (s * 32 + 16 + n16) * 8]);
            const int vc = ((s * 4 + g) ^ (n16 & 7)) * 8;
            const bf16x8 vf0 = *(const bf16x8*)(&Vl[cur][n16 * 64 + vc]);
            const bf16x8 vf1 = *(const bf16x8*)(&Vl[cur][(16 + n16) * 64 + vc]);

            #pragma unroll
            for (int it = 0; it < 2; ++it) {
                const bf16x8 qf = it ? qf1 : qf0;
                f32x4 s0 = __builtin_amdgcn_mfma_f32_16x16x32_bf16(kf0, qf, zero, 0, 0, 0);
                f32x4 s1 = __builtin_amdgcn_mfma_f32_16x16x32_bf16(kf1, qf, zero, 0, 0, 0);
                const float p0 = __builtin_amdgcn_exp2f(s0.x);
                const float p1 = __builtin_amdgcn_exp2f(s0.y);
                const float p2 = __builtin_amdgcn_exp2f(s0.z);
                const float p3 = __builtin_amdgcn_exp2f(s0.w);
                const float p4 = __builtin_amdgcn_exp2f(s1.x);
                const float p5 = __builtin_amdgcn_exp2f(s1.y);
                const float p6 = __builtin_amdgcn_exp2f(s1.z);
                const float p7 = __builtin_amdgcn_exp2f(s1.w);
                const float ps = ((p0 + p1) + (p2 + p3)) + ((p4 + p5) + (p6 + p7));
                if (it) l1 += ps; else l0 += ps;
                const unsigned W0 = pk2bf(p0, p1);
                const unsigned W1 = pk2bf(p2, p3);
                const unsigned X0 = pk2bf(p4, p5);
                const unsigned X1 = pk2bf(p6, p7);
                const int t0 = (int)(pp ? X0 : W0);
                const int t1 = (int)(pp ? X1 : W1);
                const int t2 = (int)(pp ? W0 : X0);
                const int t3 = (int)(pp ? W1 : X1);
                const int q0 = __builtin_amdgcn_ds_bpermute(aP, t0);
                const int q1 = __builtin_amdgcn_ds_bpermute(aP, t1);
                const int q2 = __builtin_amdgcn_ds_bpermute(aQ, t2);
                const int q3 = __builtin_amdgcn_ds_bpermute(aQ, t3);
                union { int u[4]; bf16x8 v; } pu;
                pu.u[0] = lowdest ? q0 : q2;
                pu.u[1] = lowdest ? q1 : q3;
                pu.u[2] = lowdest ? q2 : q0;
                pu.u[3] = lowdest ? q3 : q1;
                if (it) {
                    acc10 = __builtin_amdgcn_mfma_f32_16x16x32_bf16(vf0, pu.v, acc10, 0, 0, 0);
                    acc11 = __builtin_amdgcn_mfma_f32_16x16x32_bf16(vf1, pu.v, acc11, 0, 0, 0);
                } else {
                    acc00 = __builtin_amdgcn_mfma_f32_16x16x32_bf16(vf0, pu.v, acc00, 0, 0, 0);
                    acc01 = __builtin_amdgcn_mfma_f32_16x16x32_bf16(vf1, pu.v, acc01, 0, 0, 0);
                }
            }
        }
        __syncthreads();
        cur ^= 1;
    }

    l0 += __shfl_xor(l0, 16); l0 += __shfl_xor(l0, 32);
    l1 += __shfl_xor(l1, 16); l1 += __shfl_xor(l1, 32);

    const size_t base = (size_t)js * 8 + bh;
    if (lane < 16) {
        pl[base * NSP + i0 + n16]      = l0;
        pl[base * NSP + i0 + 16 + n16] = l1;
    }
    float* pb = pacc + base * 32 * NSP;
    #pragma unroll
    for (int r = 0; r < 4; ++r) {
        const int d0 = 4 * g + r, d1 = 16 + 4 * g + r;
        pb[(size_t)d0 * NSP + i0 + n16]      = acc00[r];
        pb[(size_t)d1 * NSP + i0 + n16]      = acc01[r];
        pb[(size_t)d0 * NSP + i0 + 16 + n16] = acc10[r];
        pb[(size_t)d1 * NSP + i0 + 16 + n16] = acc11[r];
    }
}

// ---------------- combine j-split partials (no max) ----------------
__global__ __launch_bounds__(256) void combine_kernel(
    const float* __restrict__ pacc, const float* __restrict__ pl,
    float* __restrict__ attnout)
{
    const int i  = blockIdx.x * 256 + threadIdx.x;
    const int bh = blockIdx.y;
    const int b = bh >> 2, h = bh & 3;
    float L = 0.f;
    #pragma unroll
    for (int s = 0; s < JS; ++s) L += pl[((size_t)(s * 8 + bh)) * NSP + i];
    const float invL = 1.0f / L;
    #pragma unroll
    for (int d = 0; d < 32; ++d) {
        float acc = 0.f;
        #pragma unroll
        for (int s = 0; s < JS; ++s)
            acc += pacc[(((size_t)(s * 8 + bh)) * 32 + d) * NSP + i];
        attnout[((size_t)b * CD + h * 32 + d) * NSP + i] = acc * invL;
    }
}

extern "C" void kernel_launch(void* const* d_in, const int* in_sizes, int n_in,
                              void* d_out, int out_size, void* d_ws, size_t ws_size,
                              hipStream_t stream)
{
    const float* x  = (const float*)d_in[0];
    const float* cx = (const float*)d_in[1];
    const float* Wq = (const float*)d_in[2];
    const float* bq = (const float*)d_in[3];
    const float* Wk = (const float*)d_in[4];
    const float* bk = (const float*)d_in[5];
    const float* Wv = (const float*)d_in[6];
    const float* bv = (const float*)d_in[7];
    const float* Wo = (const float*)d_in[8];
    const float* bo = (const float*)d_in[9];
    float* out = (float*)d_out;

    char* w = (char*)d_ws;
    float*  qb   = (float*)w;  w += (size_t)NB * CD * NSP * 4;        // 4 MB
    float*  kb   = (float*)w;  w += (size_t)NB * CD * NSP * 4;        // 4 MB
    float*  scq  = (float*)w;  w += 1024;
    float*  sck  = (float*)w;  w += 1024;
    ushort* Qt   = (ushort*)w; w += (size_t)NB * NH * NSP * 32 * 2;   // 2 MB
    ushort* Kt   = (ushort*)w; w += (size_t)NB * NH * NSP * 32 * 2;   // 2 MB
    ushort* V16  = (ushort*)w; w += (size_t)NB * CD * NSP * 2;        // 2 MB
    float*  pacc = (float*)w;  w += (size_t)JS * 8 * 32 * NSP * 4;    // 16 MB
    float*  pl   = (float*)w;  w += (size_t)JS * 8 * NSP * 4;         // 512 KB
    float*  attnout = (float*)w;                                      // 4 MB

    dim3 pgrid4(NSP / 1024, CD / 4, NB);
    proj_qkv<<<pgrid4, 256, 0, stream>>>(x, cx, Wq, bq, qb, Wk, bk, kb, Wv, bv, V16);
    rownorm<<<dim3(CD, NB, 2), 256, 0, stream>>>(qb, kb, scq, sck);
    pack_qk<<<dim3(NSP / 256, NB * NH), 256, 0, stream>>>(qb, kb, scq, sck, Qt, Kt);
    attn_mfma<<<dim3(1024), 256, 0, stream>>>(Qt, Kt, V16, pacc, pl);
    combine_kernel<<<dim3(NSP / 256, NB * NH), 256, 0, stream>>>(pacc, pl, attnout);
    proj_one<<<pgrid4, 256, 0, stream>>>(attnout, Wo, bo, out);
}

// Round 8
// 83.015 us; speedup vs baseline: 1.9242x; 1.9242x over previous
//
#include <hip/hip_runtime.h>
#include <hip/hip_bf16.h>
#include <math.h>

#define NSP 4096      // h*w*z = 16^3
#define CD 128        // channels
#define NB 2          // batch
#define NH 4          // heads
#define JS 4          // j-splits in attention
#define JSTEP 64
#define NSTEP ((NSP / JS) / JSTEP)   // 16

typedef __attribute__((ext_vector_type(8))) short bf16x8;   // 8 bf16 (4 VGPRs)
typedef __attribute__((ext_vector_type(4))) float f32x4;

static constexpr float QSCALE = 10.0f * 1.4426950408889634f;  // scale * log2(e)

__device__ __forceinline__ ushort f2bf(float f) {
    union { float f; unsigned u; } v; v.f = f;
    unsigned r = v.u + 0x7fffu + ((v.u >> 16) & 1u);   // RNE, finite inputs only
    return (ushort)(r >> 16);
}

// RNE pack via compiler-known builtin (emits v_cvt_pk_bf16_f32): low16=a, high16=b
__device__ __forceinline__ unsigned pk2bf(float a, float b) {
    union { __hip_bfloat162 h; unsigned u; } t;
    t.h = __float22bfloat162_rn(make_float2(a, b));
    return t.u;
}

__device__ __forceinline__ void gload_lds16(const void* g, void* l) {
    __builtin_amdgcn_global_load_lds(
        (const __attribute__((address_space(1))) unsigned int*)g,
        (__attribute__((address_space(3))) unsigned int*)l, 16, 0, 0);
}

// ---------------- cast 4 weight matrices fp32 -> bf16 ----------------
// Wall = [Wq | Wk | Wv | Wo], each 128x128 row-major (o-major, c contiguous)
__global__ __launch_bounds__(256) void wcast(
    const float* __restrict__ Wq, const float* __restrict__ Wk,
    const float* __restrict__ Wv, const float* __restrict__ Wo,
    ushort* __restrict__ Wall)
{
    const int i = (blockIdx.x * 256 + threadIdx.x) * 4;   // grid 64 -> 65536 elems
    const int m = i >> 14;                                 // which matrix
    const float* src = (m == 0) ? Wq : (m == 1) ? Wk : (m == 2) ? Wv : Wo;
    const float4 v = *(const float4*)(src + (i & 16383));
    ushort4 o;
    o.x = f2bf(v.x); o.y = f2bf(v.y); o.z = f2bf(v.z); o.w = f2bf(v.w);
    *(ushort4*)(Wall + i) = o;
}

// ---------------- transpose+cast: [b][c][n] fp32 -> [b][n][c] bf16 ----------------
// grid (NSP/64, NB, 2): z=0 -> x->Xt, z=1 -> cx->Ct. Block 256.
__global__ __launch_bounds__(256) void tcast(
    const float* __restrict__ x, const float* __restrict__ cx,
    ushort* __restrict__ Xt, ushort* __restrict__ Ct)
{
    __shared__ ushort L[64][130];   // [n_local][c], pad to 130 (65 banks-ish)
    const int t  = threadIdx.x;
    const int n0 = blockIdx.x * 64;
    const int b  = blockIdx.y;
    const float* in = (blockIdx.z == 0) ? x : cx;
    ushort* outp    = (blockIdx.z == 0) ? Xt : Ct;

    const int nl = t & 63, cq = t >> 6;
    #pragma unroll
    for (int cc = cq; cc < CD; cc += 4)
        L[nl][cc] = f2bf(in[((size_t)b * CD + cc) * NSP + n0 + nl]);
    __syncthreads();

    const int nr = t >> 2, cs = (t & 3) * 32;
    unsigned u[16];
    #pragma unroll
    for (int w = 0; w < 16; ++w)
        u[w] = (unsigned)L[nr][cs + 2 * w] | ((unsigned)L[nr][cs + 2 * w + 1] << 16);
    ushort* dst = outp + ((size_t)(b * NSP + n0 + nr)) * CD + cs;
    #pragma unroll
    for (int w = 0; w < 4; ++w)
        *(uint4*)(dst + w * 8) = make_uint4(u[4*w], u[4*w+1], u[4*w+2], u[4*w+3]);
    // second set of rows (nr covers 0..63 in two halves: t>>2 gives 0..63 already? no)
}

// NOTE: tcast above covers nr = t>>2 in 0..63 only if blockDim=256 -> t>>2 in 0..63. OK.

// ---------------- MFMA q,k,v projection ----------------
// grid (512, 2) blocks of 4 waves. blockIdx.x = n16-tile over NB*NSP; y = o-quad.
// wave w: o-tile = y*4+w. q from Xt, k/v from Ct. Outputs: qb,kb fp32 [b][c][n]; V16 bf16.
__global__ __launch_bounds__(256) void proj_qkv_mfma(
    const ushort* __restrict__ Xt, const ushort* __restrict__ Ct,
    const ushort* __restrict__ Wall,
    const float* __restrict__ Bq, const float* __restrict__ Bk, const float* __restrict__ Bv,
    float* __restrict__ qb, float* __restrict__ kb, ushort* __restrict__ V16)
{
    const int t = threadIdx.x;
    const int wid = t >> 6, lane = t & 63;
    const int g = lane >> 4, n16 = lane & 15;
    const int nt = blockIdx.x;
    const int b  = nt >> 8;
    const int nb = (nt & 255) * 16;           // n within batch
    const int o0 = (blockIdx.y * 4 + wid) * 16;

    const ushort* Wq = Wall;
    const ushort* Wk = Wall + 16384;
    const ushort* Wv = Wall + 32768;
    const size_t xrow = ((size_t)(b * NSP + nb + n16)) * CD;
    const size_t wrow = (size_t)(o0 + n16) * CD;

    f32x4 aq = {0,0,0,0}, ak = {0,0,0,0}, av = {0,0,0,0};
    #pragma unroll
    for (int ks = 0; ks < 4; ++ks) {
        const int k0 = ks * 32 + g * 8;
        const bf16x8 bx = *(const bf16x8*)(Xt + xrow + k0);
        const bf16x8 bc = *(const bf16x8*)(Ct + xrow + k0);
        const bf16x8 wqf = *(const bf16x8*)(Wq + wrow + k0);
        const bf16x8 wkf = *(const bf16x8*)(Wk + wrow + k0);
        const bf16x8 wvf = *(const bf16x8*)(Wv + wrow + k0);
        aq = __builtin_amdgcn_mfma_f32_16x16x32_bf16(wqf, bx, aq, 0, 0, 0);
        ak = __builtin_amdgcn_mfma_f32_16x16x32_bf16(wkf, bc, ak, 0, 0, 0);
        av = __builtin_amdgcn_mfma_f32_16x16x32_bf16(wvf, bc, av, 0, 0, 0);
    }
    #pragma unroll
    for (int r = 0; r < 4; ++r) {
        const int o = o0 + 4 * g + r;
        const size_t row = ((size_t)(b * CD + o)) * NSP + nb + n16;
        qb[row]  = aq[r] + Bq[o];
        kb[row]  = ak[r] + Bk[o];
        V16[row] = f2bf(av[r] + Bv[o]);
    }
}

// ---------------- MFMA output projection ----------------
// input Yt bf16 [b][n][c]; output out fp32 [b][c][n]
__global__ __launch_bounds__(256) void proj_out_mfma(
    const ushort* __restrict__ Yt, const ushort* __restrict__ Wall,
    const float* __restrict__ Bo, float* __restrict__ outp)
{
    const int t = threadIdx.x;
    const int wid = t >> 6, lane = t & 63;
    const int g = lane >> 4, n16 = lane & 15;
    const int nt = blockIdx.x;
    const int b  = nt >> 8;
    const int nb = (nt & 255) * 16;
    const int o0 = (blockIdx.y * 4 + wid) * 16;

    const ushort* Wo = Wall + 49152;
    const size_t xrow = ((size_t)(b * NSP + nb + n16)) * CD;
    const size_t wrow = (size_t)(o0 + n16) * CD;

    f32x4 a = {0,0,0,0};
    #pragma unroll
    for (int ks = 0; ks < 4; ++ks) {
        const int k0 = ks * 32 + g * 8;
        const bf16x8 bx = *(const bf16x8*)(Yt + xrow + k0);
        const bf16x8 wf = *(const bf16x8*)(Wo + wrow + k0);
        a = __builtin_amdgcn_mfma_f32_16x16x32_bf16(wf, bx, a, 0, 0, 0);
    }
    #pragma unroll
    for (int r = 0; r < 4; ++r) {
        const int o = o0 + 4 * g + r;
        outp[((size_t)(b * CD + o)) * NSP + nb + n16] = a[r] + Bo[o];
    }
}

// ---------------- per-(b,c)-row L2 norm scales over spatial N ----------------
__global__ __launch_bounds__(256) void rownorm(
    const float* __restrict__ qb, const float* __restrict__ kb,
    float* __restrict__ scq, float* __restrict__ sck)
{
    const int c = blockIdx.x, b = blockIdx.y, which = blockIdx.z;
    const float* row = (which ? kb : qb) + ((size_t)b * CD + c) * NSP;
    const int t = threadIdx.x;
    float ss = 0.f;
    for (int i = t * 4; i < NSP; i += 1024) {
        float4 v = *(const float4*)&row[i];
        ss = fmaf(v.x, v.x, fmaf(v.y, v.y, fmaf(v.z, v.z, fmaf(v.w, v.w, ss))));
    }
    #pragma unroll
    for (int off = 32; off > 0; off >>= 1) ss += __shfl_down(ss, off, 64);
    __shared__ float red[4];
    if ((t & 63) == 0) red[t >> 6] = ss;
    __syncthreads();
    if (t == 0) {
        const float total = red[0] + red[1] + red[2] + red[3];
        const float sc = (which ? 1.0f : QSCALE) / fmaxf(sqrtf(total), 1e-12f);
        (which ? sck : scq)[b * CD + c] = sc;
    }
}

// ---------------- pack q,k -> bf16 chunk-major [bh][n/64][c=d/8][n%64][8] ----------------
__global__ __launch_bounds__(256) void pack_qk(
    const float* __restrict__ qb, const float* __restrict__ kb,
    const float* __restrict__ scq, const float* __restrict__ sck,
    ushort* __restrict__ Qt, ushort* __restrict__ Kt)
{
    const int n  = blockIdx.x * 256 + threadIdx.x;
    const int bh = blockIdx.y;
    const int b = bh >> 2, h = bh & 3;
    unsigned qw[16], kw[16];
    #pragma unroll
    for (int dp = 0; dp < 16; ++dp) {
        const int gr = b * CD + h * 32 + 2 * dp;
        const float fq0 = qb[(size_t)gr * NSP + n] * scq[gr];
        const float fq1 = qb[(size_t)(gr + 1) * NSP + n] * scq[gr + 1];
        const float fk0 = kb[(size_t)gr * NSP + n] * sck[gr];
        const float fk1 = kb[(size_t)(gr + 1) * NSP + n] * sck[gr + 1];
        qw[dp] = pk2bf(fq0, fq1);
        kw[dp] = pk2bf(fk0, fk1);
    }
    const int jb = n >> 6, jr = n & 63;
    const size_t base = ((size_t)(bh * (NSP / 64) + jb)) * 4;
    #pragma unroll
    for (int c = 0; c < 4; ++c) {
        *(uint4*)(Qt + (base + c) * 512 + jr * 8) =
            make_uint4(qw[4*c], qw[4*c+1], qw[4*c+2], qw[4*c+3]);
        *(uint4*)(Kt + (base + c) * 512 + jr * 8) =
            make_uint4(kw[4*c], kw[4*c+1], kw[4*c+2], kw[4*c+3]);
    }
}

// ---------------- MFMA flash attention partials (LDS-staged K/V, 16 q/wave) --------
// grid 2048 blocks, 256 threads (4 waves). bh=f&7, it=(f>>3)&63, js=f>>9.
__global__ __launch_bounds__(256, 8) void attn_mfma(
    const ushort* __restrict__ Qt, const ushort* __restrict__ Kt,
    const ushort* __restrict__ V16,
    float* __restrict__ pacc, float* __restrict__ pl)
{
    __shared__ __align__(16) ushort Kl[2][2048];   // [c=d/8][64 j][8]  (4KB each)
    __shared__ __align__(16) ushort Vl[2][2048];   // [d][8 chunks^swz][8] (4KB each)

    const int t = threadIdx.x;
    const int wid = t >> 6, lane = t & 63;
    const int g = lane >> 4, n16 = lane & 15;
    const int f = blockIdx.x;
    const int bh = f & 7, it64 = (f >> 3) & 63, js = f >> 9;
    const int b = bh >> 2, h = bh & 3;
    const int i0 = it64 * 64 + wid * 16;

    const ushort* QtB = Qt + (size_t)bh * NSP * 32;
    const ushort* KtB = Kt + (size_t)bh * NSP * 32;
    const ushort* Vb  = V16 + (size_t)(b * CD + h * 32) * NSP;

    const bf16x8 qf = *(const bf16x8*)(QtB + ((size_t)(i0 >> 6) * 4 + g) * 512
                                           + ((i0 & 63) + n16) * 8);

    f32x4 acc0 = {0,0,0,0}, acc1 = {0,0,0,0};
    float l0 = 0.f;
    const f32x4 zero = {0,0,0,0};

    const bool pp      = (g & 1);
    const bool lowdest = (g < 2);
    const int srcA4 = ((32 * (g & 1)) + n16) * 4;
    const int srcB4 = srcA4 + 64;
    const int aP = lowdest ? srcA4 : srcB4;
    const int aQ = lowdest ? srcB4 : srcA4;

    const int vd  = wid * 8 + (lane >> 3);
    const int vsw = (lane & 7) ^ (lane >> 3);
    auto stageK = [&](int buf, int jt) {
        const ushort* gsrc = KtB + ((size_t)(jt >> 6) * 4 + wid) * 512 + lane * 8;
        gload_lds16(gsrc, &Kl[buf][wid * 512]);
    };
    auto stageV = [&](int buf, int jt) {
        const ushort* gsrc = Vb + (size_t)vd * NSP + jt + vsw * 8;
        gload_lds16(gsrc, &Vl[buf][wid * 512]);
    };

    const int jbeg = js * (NSP / JS);

    stageK(0, jbeg); stageV(0, jbeg);
    __syncthreads();

    int cur = 0;
    for (int step = 0; step < NSTEP; ++step) {
        const int jt = jbeg + step * JSTEP;
        if (step + 1 < NSTEP) { stageK(cur ^ 1, jt + JSTEP); stageV(cur ^ 1, jt + JSTEP); }

        #pragma unroll
        for (int s = 0; s < 2; ++s) {
            const bf16x8 kf0 = *(const bf16x8*)(&Kl[cur][g * 512 + (s * 32 + n16) * 8]);
            const bf16x8 kf1 = *(const bf16x8*)(&Kl[cur][g * 512 + (s * 32 + 16 + n16) * 8]);
            const int vc = ((s * 4 + g) ^ (n16 & 7)) * 8;
            const bf16x8 vf0 = *(const bf16x8*)(&Vl[cur][n16 * 64 + vc]);
            const bf16x8 vf1 = *(const bf16x8*)(&Vl[cur][(16 + n16) * 64 + vc]);

            f32x4 s0 = __builtin_amdgcn_mfma_f32_16x16x32_bf16(kf0, qf, zero, 0, 0, 0);
            f32x4 s1 = __builtin_amdgcn_mfma_f32_16x16x32_bf16(kf1, qf, zero, 0, 0, 0);
            const float p0 = __builtin_amdgcn_exp2f(s0.x);
            const float p1 = __builtin_amdgcn_exp2f(s0.y);
            const float p2 = __builtin_amdgcn_exp2f(s0.z);
            const float p3 = __builtin_amdgcn_exp2f(s0.w);
            const float p4 = __builtin_amdgcn_exp2f(s1.x);
            const float p5 = __builtin_amdgcn_exp2f(s1.y);
            const float p6 = __builtin_amdgcn_exp2f(s1.z);
            const float p7 = __builtin_amdgcn_exp2f(s1.w);
            l0 += ((p0 + p1) + (p2 + p3)) + ((p4 + p5) + (p6 + p7));
            const unsigned W0 = pk2bf(p0, p1);
            const unsigned W1 = pk2bf(p2, p3);
            const unsigned X0 = pk2bf(p4, p5);
            const unsigned X1 = pk2bf(p6, p7);
            const int t0 = (int)(pp ? X0 : W0);
            const int t1 = (int)(pp ? X1 : W1);
            const int t2 = (int)(pp ? W0 : X0);
            const int t3 = (int)(pp ? W1 : X1);
            const int q0 = __builtin_amdgcn_ds_bpermute(aP, t0);
            const int q1 = __builtin_amdgcn_ds_bpermute(aP, t1);
            const int q2 = __builtin_amdgcn_ds_bpermute(aQ, t2);
            const int q3 = __builtin_amdgcn_ds_bpermute(aQ, t3);
            union { int u[4]; bf16x8 v; } pu;
            pu.u[0] = lowdest ? q0 : q2;
            pu.u[1] = lowdest ? q1 : q3;
            pu.u[2] = lowdest ? q2 : q0;
            pu.u[3] = lowdest ? q3 : q1;
            acc0 = __builtin_amdgcn_mfma_f32_16x16x32_bf16(vf0, pu.v, acc0, 0, 0, 0);
            acc1 = __builtin_amdgcn_mfma_f32_16x16x32_bf16(vf1, pu.v, acc1, 0, 0, 0);
        }
        __syncthreads();
        cur ^= 1;
    }

    l0 += __shfl_xor(l0, 16); l0 += __shfl_xor(l0, 32);

    const size_t base = (size_t)js * 8 + bh;
    if (lane < 16) pl[base * NSP + i0 + n16] = l0;
    float* pb = pacc + base * 32 * NSP;
    #pragma unroll
    for (int r = 0; r < 4; ++r) {
        pb[(size_t)(4 * g + r) * NSP + i0 + n16]      = acc0[r];
        pb[(size_t)(16 + 4 * g + r) * NSP + i0 + n16] = acc1[r];
    }
}

// ---------------- combine partials -> Yt bf16 [b][n][c] ----------------
__global__ __launch_bounds__(256) void combine_kernel(
    const float* __restrict__ pacc, const float* __restrict__ pl,
    ushort* __restrict__ Yt)
{
    const int i  = blockIdx.x * 256 + threadIdx.x;
    const int bh = blockIdx.y;
    const int b = bh >> 2, h = bh & 3;
    float L = 0.f;
    #pragma unroll
    for (int s = 0; s < JS; ++s) L += pl[((size_t)(s * 8 + bh)) * NSP + i];
    const float invL = 1.0f / L;
    unsigned u[16];
    #pragma unroll
    for (int dp = 0; dp < 16; ++dp) {
        float a0 = 0.f, a1 = 0.f;
        #pragma unroll
        for (int s = 0; s < JS; ++s) {
            const size_t pb = ((size_t)(s * 8 + bh)) * 32;
            a0 += pacc[(pb + 2 * dp)     * NSP + i];
            a1 += pacc[(pb + 2 * dp + 1) * NSP + i];
        }
        u[dp] = pk2bf(a0 * invL, a1 * invL);
    }
    ushort* dst = Yt + ((size_t)(b * NSP + i)) * CD + h * 32;
    #pragma unroll
    for (int w = 0; w < 4; ++w)
        *(uint4*)(dst + w * 8) = make_uint4(u[4*w], u[4*w+1], u[4*w+2], u[4*w+3]);
}

extern "C" void kernel_launch(void* const* d_in, const int* in_sizes, int n_in,
                              void* d_out, int out_size, void* d_ws, size_t ws_size,
                              hipStream_t stream)
{
    const float* x  = (const float*)d_in[0];
    const float* cx = (const float*)d_in[1];
    const float* Wq = (const float*)d_in[2];
    const float* bq = (const float*)d_in[3];
    const float* Wk = (const float*)d_in[4];
    const float* bk = (const float*)d_in[5];
    const float* Wv = (const float*)d_in[6];
    const float* bv = (const float*)d_in[7];
    const float* Wo = (const float*)d_in[8];
    const float* bo = (const float*)d_in[9];
    float* out = (float*)d_out;

    char* w = (char*)d_ws;
    float*  qb   = (float*)w;  w += (size_t)NB * CD * NSP * 4;        // 4 MB
    float*  kb   = (float*)w;  w += (size_t)NB * CD * NSP * 4;        // 4 MB
    float*  scq  = (float*)w;  w += 1024;
    float*  sck  = (float*)w;  w += 1024;
    ushort* Qt   = (ushort*)w; w += (size_t)NB * NH * NSP * 32 * 2;   // 2 MB
    ushort* Kt   = (ushort*)w; w += (size_t)NB * NH * NSP * 32 * 2;   // 2 MB
    ushort* V16  = (ushort*)w; w += (size_t)NB * CD * NSP * 2;        // 2 MB
    float*  pacc = (float*)w;  w += (size_t)JS * 8 * 32 * NSP * 4;    // 16 MB
    float*  pl   = (float*)w;  w += (size_t)JS * 8 * NSP * 4;         // 512 KB
    ushort* Xt   = (ushort*)w; w += (size_t)NB * NSP * CD * 2;        // 2 MB
    ushort* Ct   = (ushort*)w; w += (size_t)NB * NSP * CD * 2;        // 2 MB
    ushort* Yt   = (ushort*)w; w += (size_t)NB * NSP * CD * 2;        // 2 MB
    ushort* Wall = (ushort*)w;                                        // 128 KB

    wcast<<<dim3(64), 256, 0, stream>>>(Wq, Wk, Wv, Wo, Wall);
    tcast<<<dim3(NSP / 64, NB, 2), 256, 0, stream>>>(x, cx, Xt, Ct);
    proj_qkv_mfma<<<dim3(512, 2), 256, 0, stream>>>(Xt, Ct, Wall, bq, bk, bv, qb, kb, V16);
    rownorm<<<dim3(CD, NB, 2), 256, 0, stream>>>(qb, kb, scq, sck);
    pack_qk<<<dim3(NSP / 256, NB * NH), 256, 0, stream>>>(qb, kb, scq, sck, Qt, Kt);
    attn_mfma<<<dim3(2048), 256, 0, stream>>>(Qt, Kt, V16, pacc, pl);
    combine_kernel<<<dim3(NSP / 256, NB * NH), 256, 0, stream>>>(pacc, pl, Yt);
    proj_out_mfma<<<dim3(512, 2), 256, 0, stream>>>(Yt, Wall, bo, out);
}

// Round 9
// 77.767 us; speedup vs baseline: 2.0541x; 1.0675x over previous
//
#include <hip/hip_runtime.h>
#include <hip/hip_bf16.h>
#include <math.h>

#define NSP 4096      // h*w*z = 16^3
#define CD 128        // channels
#define NB 2          // batch
#define NH 4          // heads
#define JS 4          // j-splits in attention
#define JSTEP 64
#define NSTEP ((NSP / JS) / JSTEP)   // 16

typedef __attribute__((ext_vector_type(8))) short bf16x8;   // 8 bf16 (4 VGPRs)
typedef __attribute__((ext_vector_type(4))) float f32x4;

static constexpr float QSCALE = 10.0f * 1.4426950408889634f;  // scale * log2(e)

__device__ __forceinline__ ushort f2bf(float f) {
    union { float f; unsigned u; } v; v.f = f;
    unsigned r = v.u + 0x7fffu + ((v.u >> 16) & 1u);   // RNE, finite inputs only
    return (ushort)(r >> 16);
}
__device__ __forceinline__ float bf2f(ushort u) {
    union { unsigned u; float f; } v; v.u = ((unsigned)u) << 16;
    return v.f;
}
// RNE pack via compiler builtin (v_cvt_pk_bf16_f32): low16=a, high16=b
__device__ __forceinline__ unsigned pk2bf(float a, float b) {
    union { __hip_bfloat162 h; unsigned u; } t;
    t.h = __float22bfloat162_rn(make_float2(a, b));
    return t.u;
}
__device__ __forceinline__ void gload_lds16(const void* g, void* l) {
    __builtin_amdgcn_global_load_lds(
        (const __attribute__((address_space(1))) unsigned int*)g,
        (__attribute__((address_space(3))) unsigned int*)l, 16, 0, 0);
}

// ---------------- fused cast: transpose x,cx -> bf16 [b][n][c]; weights -> bf16 ----
// grid (80, NB, 2): x<64 -> tcast; x>=64 -> weight cast (matrix m = z*2+y).
__global__ __launch_bounds__(256) void cast_all(
    const float* __restrict__ x, const float* __restrict__ cx,
    const float* __restrict__ Wq, const float* __restrict__ Wk,
    const float* __restrict__ Wv, const float* __restrict__ Wo,
    ushort* __restrict__ Xt, ushort* __restrict__ Ct, ushort* __restrict__ Wall)
{
    const int t = threadIdx.x;
    if (blockIdx.x >= 64) {
        const int sub = blockIdx.x - 64;                 // 0..15
        const int m = blockIdx.z * 2 + blockIdx.y;       // 0..3
        const float* src = (m == 0) ? Wq : (m == 1) ? Wk : (m == 2) ? Wv : Wo;
        const int off = sub * 1024 + t * 4;
        const float4 v = *(const float4*)(src + off);
        ushort4 o;
        o.x = f2bf(v.x); o.y = f2bf(v.y); o.z = f2bf(v.z); o.w = f2bf(v.w);
        *(ushort4*)(Wall + m * 16384 + off) = o;
        return;
    }
    __shared__ ushort L[64][130];
    const int n0 = blockIdx.x * 64;
    const int b  = blockIdx.y;
    const float* in = (blockIdx.z == 0) ? x : cx;
    ushort* outp    = (blockIdx.z == 0) ? Xt : Ct;
    const int nl = t & 63, cq = t >> 6;
    #pragma unroll
    for (int cc = cq; cc < CD; cc += 4)
        L[nl][cc] = f2bf(in[((size_t)b * CD + cc) * NSP + n0 + nl]);
    __syncthreads();
    const int nr = t >> 2, cs = (t & 3) * 32;
    unsigned u[16];
    #pragma unroll
    for (int w = 0; w < 16; ++w)
        u[w] = (unsigned)L[nr][cs + 2 * w] | ((unsigned)L[nr][cs + 2 * w + 1] << 16);
    ushort* dst = outp + ((size_t)(b * NSP + n0 + nr)) * CD + cs;
    #pragma unroll
    for (int w = 0; w < 4; ++w)
        *(uint4*)(dst + w * 8) = make_uint4(u[4*w], u[4*w+1], u[4*w+2], u[4*w+3]);
}

// ---------------- MFMA q,k,v projection + norm partials ----------------
// grid (512, 2). qh,kh bf16 [b][c][n]; V16 bf16 [b][c][n]; partQ/partK[(b*CD+o)*256+xblk]
__global__ __launch_bounds__(256) void proj_qkv_mfma(
    const ushort* __restrict__ Xt, const ushort* __restrict__ Ct,
    const ushort* __restrict__ Wall,
    const float* __restrict__ Bq, const float* __restrict__ Bk, const float* __restrict__ Bv,
    ushort* __restrict__ qh, ushort* __restrict__ kh, ushort* __restrict__ V16,
    float* __restrict__ partQ, float* __restrict__ partK)
{
    const int t = threadIdx.x;
    const int wid = t >> 6, lane = t & 63;
    const int g = lane >> 4, n16 = lane & 15;
    const int nt = blockIdx.x;
    const int b  = nt >> 8;
    const int xblk = nt & 255;
    const int nb = xblk * 16;
    const int o0 = (blockIdx.y * 4 + wid) * 16;

    const ushort* Wq = Wall;
    const ushort* Wk = Wall + 16384;
    const ushort* Wv = Wall + 32768;
    const size_t xrow = ((size_t)(b * NSP + nb + n16)) * CD;
    const size_t wrow = (size_t)(o0 + n16) * CD;

    f32x4 aq = {0,0,0,0}, ak = {0,0,0,0}, av = {0,0,0,0};
    #pragma unroll
    for (int ks = 0; ks < 4; ++ks) {
        const int k0 = ks * 32 + g * 8;
        const bf16x8 bx = *(const bf16x8*)(Xt + xrow + k0);
        const bf16x8 bc = *(const bf16x8*)(Ct + xrow + k0);
        const bf16x8 wqf = *(const bf16x8*)(Wq + wrow + k0);
        const bf16x8 wkf = *(const bf16x8*)(Wk + wrow + k0);
        const bf16x8 wvf = *(const bf16x8*)(Wv + wrow + k0);
        aq = __builtin_amdgcn_mfma_f32_16x16x32_bf16(wqf, bx, aq, 0, 0, 0);
        ak = __builtin_amdgcn_mfma_f32_16x16x32_bf16(wkf, bc, ak, 0, 0, 0);
        av = __builtin_amdgcn_mfma_f32_16x16x32_bf16(wvf, bc, av, 0, 0, 0);
    }
    float sq[4], sk[4];
    #pragma unroll
    for (int r = 0; r < 4; ++r) {
        const int o = o0 + 4 * g + r;
        const size_t row = ((size_t)(b * CD + o)) * NSP + nb + n16;
        const float qv = aq[r] + Bq[o];
        const float kv = ak[r] + Bk[o];
        qh[row]  = f2bf(qv);
        kh[row]  = f2bf(kv);
        V16[row] = f2bf(av[r] + Bv[o]);
        sq[r] = qv * qv; sk[r] = kv * kv;
    }
    #pragma unroll
    for (int r = 0; r < 4; ++r) {
        #pragma unroll
        for (int off = 1; off < 16; off <<= 1) {
            sq[r] += __shfl_xor(sq[r], off);
            sk[r] += __shfl_xor(sk[r], off);
        }
    }
    if (n16 == 0) {
        #pragma unroll
        for (int r = 0; r < 4; ++r) {
            const int ch = b * CD + o0 + 4 * g + r;
            partQ[(size_t)ch * 256 + xblk] = sq[r];
            partK[(size_t)ch * 256 + xblk] = sk[r];
        }
    }
}

// ---------------- reduce norm partials -> scales ----------------
// grid 512: blockIdx.x = ch | (isK<<8)
__global__ __launch_bounds__(256) void normfin(
    const float* __restrict__ partQ, const float* __restrict__ partK,
    float* __restrict__ scq, float* __restrict__ sck)
{
    const int ch = blockIdx.x & 255, isK = blockIdx.x >> 8;
    const float* p = (isK ? partK : partQ) + (size_t)ch * 256;
    const int t = threadIdx.x;
    float v = p[t];
    #pragma unroll
    for (int off = 32; off > 0; off >>= 1) v += __shfl_down(v, off, 64);
    __shared__ float red[4];
    if ((t & 63) == 0) red[t >> 6] = v;
    __syncthreads();
    if (t == 0) {
        const float total = red[0] + red[1] + red[2] + red[3];
        const float sc = (isK ? 1.0f : QSCALE) / fmaxf(sqrtf(total), 1e-12f);
        (isK ? sck : scq)[ch] = sc;
    }
}

// ---------------- pack q,k -> bf16 chunk-major [bh][n/64][c=d/8][n%64][8] ----------------
__global__ __launch_bounds__(256) void pack_qk(
    const ushort* __restrict__ qh, const ushort* __restrict__ kh,
    const float* __restrict__ scq, const float* __restrict__ sck,
    ushort* __restrict__ Qt, ushort* __restrict__ Kt)
{
    const int n  = blockIdx.x * 256 + threadIdx.x;
    const int bh = blockIdx.y;
    const int b = bh >> 2, h = bh & 3;
    unsigned qw[16], kw[16];
    #pragma unroll
    for (int dp = 0; dp < 16; ++dp) {
        const int gr = b * CD + h * 32 + 2 * dp;
        const float fq0 = bf2f(qh[(size_t)gr * NSP + n]) * scq[gr];
        const float fq1 = bf2f(qh[(size_t)(gr + 1) * NSP + n]) * scq[gr + 1];
        const float fk0 = bf2f(kh[(size_t)gr * NSP + n]) * sck[gr];
        const float fk1 = bf2f(kh[(size_t)(gr + 1) * NSP + n]) * sck[gr + 1];
        qw[dp] = pk2bf(fq0, fq1);
        kw[dp] = pk2bf(fk0, fk1);
    }
    const int jb = n >> 6, jr = n & 63;
    const size_t base = ((size_t)(bh * (NSP / 64) + jb)) * 4;
    #pragma unroll
    for (int c = 0; c < 4; ++c) {
        *(uint4*)(Qt + (base + c) * 512 + jr * 8) =
            make_uint4(qw[4*c], qw[4*c+1], qw[4*c+2], qw[4*c+3]);
        *(uint4*)(Kt + (base + c) * 512 + jr * 8) =
            make_uint4(kw[4*c], kw[4*c+1], kw[4*c+2], kw[4*c+3]);
    }
}

// ---------------- MFMA flash attention partials (no bpermute) ----------------
// grid 2048, 256 threads (4 waves). bh=f&7, it=(f>>3)&63, js=f>>9.
// QK output leaves lane (g,n16) with P at j-offsets {4g+r, 16+4g+r}; V fragment is
// loaded in the SAME j-order (two ds_read_b64 per row), so pk2bf(p) IS the B-frag.
// pacc stored as packed bf16 pairs (u32), pair p covers d = 2p, 2p+1.
__global__ __launch_bounds__(256, 8) void attn_mfma(
    const ushort* __restrict__ Qt, const ushort* __restrict__ Kt,
    const ushort* __restrict__ V16,
    unsigned* __restrict__ pacc, float* __restrict__ pl)
{
    __shared__ __align__(16) ushort Kl[2][2048];   // [c=d/8][64 j][8]
    __shared__ __align__(16) ushort Vl[2][2048];   // [d][chunk16 ^ (d&7)][8]

    const int t = threadIdx.x;
    const int wid = t >> 6, lane = t & 63;
    const int g = lane >> 4, n16 = lane & 15;
    const int f = blockIdx.x;
    const int bh = f & 7, it64 = (f >> 3) & 63, js = f >> 9;
    const int b = bh >> 2, h = bh & 3;
    const int i0 = it64 * 64 + wid * 16;

    const ushort* QtB = Qt + (size_t)bh * NSP * 32;
    const ushort* KtB = Kt + (size_t)bh * NSP * 32;
    const ushort* Vb  = V16 + (size_t)(b * CD + h * 32) * NSP;

    const bf16x8 qf = *(const bf16x8*)(QtB + ((size_t)(i0 >> 6) * 4 + g) * 512
                                           + ((i0 & 63) + n16) * 8);

    f32x4 acc0 = {0,0,0,0}, acc1 = {0,0,0,0};
    float l0 = 0.f;
    const f32x4 zero = {0,0,0,0};

    const int vd  = wid * 8 + (lane >> 3);          // V row this lane stages
    const int vsw = (lane & 7) ^ (lane >> 3);       // 16B-chunk XOR swizzle
    auto stageK = [&](int buf, int jt) {
        const ushort* gsrc = KtB + ((size_t)(jt >> 6) * 4 + wid) * 512 + lane * 8;
        gload_lds16(gsrc, &Kl[buf][wid * 512]);
    };
    auto stageV = [&](int buf, int jt) {
        const ushort* gsrc = Vb + (size_t)vd * NSP + jt + vsw * 8;
        gload_lds16(gsrc, &Vl[buf][wid * 512]);
    };

    const int jbeg = js * (NSP / JS);
    stageK(0, jbeg); stageV(0, jbeg);
    __syncthreads();

    int cur = 0;
    for (int step = 0; step < NSTEP; ++step) {
        const int jt = jbeg + step * JSTEP;
        if (step + 1 < NSTEP) { stageK(cur ^ 1, jt + JSTEP); stageV(cur ^ 1, jt + JSTEP); }

        #pragma unroll
        for (int s = 0; s < 2; ++s) {
            const bf16x8 kf0 = *(const bf16x8*)(&Kl[cur][g * 512 + (s * 32 + n16) * 8]);
            const bf16x8 kf1 = *(const bf16x8*)(&Kl[cur][g * 512 + (s * 32 + 16 + n16) * 8]);
            // V in P's j-order: chunks (4s+(g>>1))^swz and (4s+2+(g>>1))^swz, half g&1
            const int c0 = ((4 * s + (g >> 1)) ^ (n16 & 7)) * 8 + (g & 1) * 4;
            const int c1 = ((4 * s + 2 + (g >> 1)) ^ (n16 & 7)) * 8 + (g & 1) * 4;
            union { uint2 u2[2]; bf16x8 v; } v0, v1;
            v0.u2[0] = *(const uint2*)(&Vl[cur][n16 * 64 + c0]);
            v0.u2[1] = *(const uint2*)(&Vl[cur][n16 * 64 + c1]);
            v1.u2[0] = *(const uint2*)(&Vl[cur][(16 + n16) * 64 + c0]);
            v1.u2[1] = *(const uint2*)(&Vl[cur][(16 + n16) * 64 + c1]);

            f32x4 s0 = __builtin_amdgcn_mfma_f32_16x16x32_bf16(kf0, qf, zero, 0, 0, 0);
            f32x4 s1 = __builtin_amdgcn_mfma_f32_16x16x32_bf16(kf1, qf, zero, 0, 0, 0);
            const float p0 = __builtin_amdgcn_exp2f(s0.x);
            const float p1 = __builtin_amdgcn_exp2f(s0.y);
            const float p2 = __builtin_amdgcn_exp2f(s0.z);
            const float p3 = __builtin_amdgcn_exp2f(s0.w);
            const float p4 = __builtin_amdgcn_exp2f(s1.x);
            const float p5 = __builtin_amdgcn_exp2f(s1.y);
            const float p6 = __builtin_amdgcn_exp2f(s1.z);
            const float p7 = __builtin_amdgcn_exp2f(s1.w);
            l0 += ((p0 + p1) + (p2 + p3)) + ((p4 + p5) + (p6 + p7));
            union { unsigned u[4]; bf16x8 v; } pf;
            pf.u[0] = pk2bf(p0, p1);
            pf.u[1] = pk2bf(p2, p3);
            pf.u[2] = pk2bf(p4, p5);
            pf.u[3] = pk2bf(p6, p7);
            acc0 = __builtin_amdgcn_mfma_f32_16x16x32_bf16(v0.v, pf.v, acc0, 0, 0, 0);
            acc1 = __builtin_amdgcn_mfma_f32_16x16x32_bf16(v1.v, pf.v, acc1, 0, 0, 0);
        }
        __syncthreads();
        cur ^= 1;
    }

    l0 += __shfl_xor(l0, 16); l0 += __shfl_xor(l0, 32);

    const size_t base = (size_t)js * 8 + bh;
    if (lane < 16) pl[base * NSP + i0 + n16] = l0;
    unsigned* pb = pacc + base * 16 * NSP;
    const int col = i0 + n16;
    pb[(size_t)(2 * g)     * NSP + col] = pk2bf(acc0[0], acc0[1]);
    pb[(size_t)(2 * g + 1) * NSP + col] = pk2bf(acc0[2], acc0[3]);
    pb[(size_t)(8 + 2 * g)     * NSP + col] = pk2bf(acc1[0], acc1[1]);
    pb[(size_t)(8 + 2 * g + 1) * NSP + col] = pk2bf(acc1[2], acc1[3]);
}

// ---------------- combine partials -> Yt bf16 [b][n][c] ----------------
__global__ __launch_bounds__(256) void combine_kernel(
    const unsigned* __restrict__ pacc, const float* __restrict__ pl,
    ushort* __restrict__ Yt)
{
    const int i  = blockIdx.x * 256 + threadIdx.x;
    const int bh = blockIdx.y;
    const int b = bh >> 2, h = bh & 3;
    float L = 0.f;
    #pragma unroll
    for (int s = 0; s < JS; ++s) L += pl[((size_t)(s * 8 + bh)) * NSP + i];
    const float invL = 1.0f / L;
    unsigned u[16];
    #pragma unroll
    for (int dp = 0; dp < 16; ++dp) {
        float a0 = 0.f, a1 = 0.f;
        #pragma unroll
        for (int s = 0; s < JS; ++s) {
            const unsigned w = pacc[(((size_t)(s * 8 + bh)) * 16 + dp) * NSP + i];
            union { unsigned u; float f; } lo, hi;
            lo.u = w << 16; hi.u = w & 0xffff0000u;
            a0 += lo.f; a1 += hi.f;
        }
        u[dp] = pk2bf(a0 * invL, a1 * invL);
    }
    ushort* dst = Yt + ((size_t)(b * NSP + i)) * CD + h * 32;
    #pragma unroll
    for (int w = 0; w < 4; ++w)
        *(uint4*)(dst + w * 8) = make_uint4(u[4*w], u[4*w+1], u[4*w+2], u[4*w+3]);
}

// ---------------- MFMA output projection ----------------
__global__ __launch_bounds__(256) void proj_out_mfma(
    const ushort* __restrict__ Yt, const ushort* __restrict__ Wall,
    const float* __restrict__ Bo, float* __restrict__ outp)
{
    const int t = threadIdx.x;
    const int wid = t >> 6, lane = t & 63;
    const int g = lane >> 4, n16 = lane & 15;
    const int nt = blockIdx.x;
    const int b  = nt >> 8;
    const int nb = (nt & 255) * 16;
    const int o0 = (blockIdx.y * 4 + wid) * 16;

    const ushort* Wo = Wall + 49152;
    const size_t xrow = ((size_t)(b * NSP + nb + n16)) * CD;
    const size_t wrow = (size_t)(o0 + n16) * CD;

    f32x4 a = {0,0,0,0};
    #pragma unroll
    for (int ks = 0; ks < 4; ++ks) {
        const int k0 = ks * 32 + g * 8;
        const bf16x8 bx = *(const bf16x8*)(Yt + xrow + k0);
        const bf16x8 wf = *(const bf16x8*)(Wo + wrow + k0);
        a = __builtin_amdgcn_mfma_f32_16x16x32_bf16(wf, bx, a, 0, 0, 0);
    }
    #pragma unroll
    for (int r = 0; r < 4; ++r) {
        const int o = o0 + 4 * g + r;
        outp[((size_t)(b * CD + o)) * NSP + nb + n16] = a[r] + Bo[o];
    }
}

extern "C" void kernel_launch(void* const* d_in, const int* in_sizes, int n_in,
                              void* d_out, int out_size, void* d_ws, size_t ws_size,
                              hipStream_t stream)
{
    const float* x  = (const float*)d_in[0];
    const float* cx = (const float*)d_in[1];
    const float* Wq = (const float*)d_in[2];
    const float* bq = (const float*)d_in[3];
    const float* Wk = (const float*)d_in[4];
    const float* bk = (const float*)d_in[5];
    const float* Wv = (const float*)d_in[6];
    const float* bv = (const float*)d_in[7];
    const float* Wo = (const float*)d_in[8];
    const float* bo = (const float*)d_in[9];
    float* out = (float*)d_out;

    char* w = (char*)d_ws;
    ushort*  qh   = (ushort*)w;  w += (size_t)NB * CD * NSP * 2;        // 2 MB
    ushort*  kh   = (ushort*)w;  w += (size_t)NB * CD * NSP * 2;        // 2 MB
    float*   scq  = (float*)w;   w += 1024;
    float*   sck  = (float*)w;   w += 1024;
    float*   partQ = (float*)w;  w += (size_t)NB * CD * 256 * 4;        // 256 KB
    float*   partK = (float*)w;  w += (size_t)NB * CD * 256 * 4;        // 256 KB
    ushort*  Qt   = (ushort*)w;  w += (size_t)NB * NH * NSP * 32 * 2;   // 2 MB
    ushort*  Kt   = (ushort*)w;  w += (size_t)NB * NH * NSP * 32 * 2;   // 2 MB
    ushort*  V16  = (ushort*)w;  w += (size_t)NB * CD * NSP * 2;        // 2 MB
    unsigned* pacc = (unsigned*)w; w += (size_t)JS * 8 * 16 * NSP * 4;  // 8 MB
    float*   pl   = (float*)w;   w += (size_t)JS * 8 * NSP * 4;         // 512 KB
    ushort*  Xt   = (ushort*)w;  w += (size_t)NB * NSP * CD * 2;        // 2 MB
    ushort*  Ct   = (ushort*)w;  w += (size_t)NB * NSP * CD * 2;        // 2 MB
    ushort*  Yt   = (ushort*)w;  w += (size_t)NB * NSP * CD * 2;        // 2 MB
    ushort*  Wall = (ushort*)w;                                         // 128 KB

    cast_all<<<dim3(80, NB, 2), 256, 0, stream>>>(x, cx, Wq, Wk, Wv, Wo, Xt, Ct, Wall);
    proj_qkv_mfma<<<dim3(512, 2), 256, 0, stream>>>(Xt, Ct, Wall, bq, bk, bv,
                                                    qh, kh, V16, partQ, partK);
    normfin<<<dim3(512), 256, 0, stream>>>(partQ, partK, scq, sck);
    pack_qk<<<dim3(NSP / 256, NB * NH), 256, 0, stream>>>(qh, kh, scq, sck, Qt, Kt);
    attn_mfma<<<dim3(2048), 256, 0, stream>>>(Qt, Kt, V16, pacc, pl);
    combine_kernel<<<dim3(NSP / 256, NB * NH), 256, 0, stream>>>(pacc, pl, Yt);
    proj_out_mfma<<<dim3(512, 2), 256, 0, stream>>>(Yt, Wall, bo, out);
}

// Round 10
// 72.904 us; speedup vs baseline: 2.1911x; 1.0667x over previous
//
#include <hip/hip_runtime.h>
#include <hip/hip_bf16.h>
#include <math.h>

#define NSP 4096      // h*w*z = 16^3
#define CD 128        // channels
#define NB 2          // batch
#define NH 4          // heads
#define JS 4          // j-splits in attention
#define JSTEP 64
#define NSTEP ((NSP / JS) / JSTEP)   // 16

typedef __attribute__((ext_vector_type(8))) short bf16x8;   // 8 bf16 (4 VGPRs)
typedef __attribute__((ext_vector_type(4))) float f32x4;

static constexpr float QSCALE = 10.0f * 1.4426950408889634f;  // scale * log2(e)

__device__ __forceinline__ ushort f2bf(float f) {
    union { float f; unsigned u; } v; v.f = f;
    unsigned r = v.u + 0x7fffu + ((v.u >> 16) & 1u);   // RNE, finite inputs only
    return (ushort)(r >> 16);
}
__device__ __forceinline__ float bf2f(ushort u) {
    union { unsigned u; float f; } v; v.u = ((unsigned)u) << 16;
    return v.f;
}
// RNE pack via compiler builtin (v_cvt_pk_bf16_f32): low16=a, high16=b
__device__ __forceinline__ unsigned pk2bf(float a, float b) {
    union { __hip_bfloat162 h; unsigned u; } t;
    t.h = __float22bfloat162_rn(make_float2(a, b));
    return t.u;
}
__device__ __forceinline__ void gload_lds16(const void* g, void* l) {
    __builtin_amdgcn_global_load_lds(
        (const __attribute__((address_space(1))) unsigned int*)g,
        (__attribute__((address_space(3))) unsigned int*)l, 16, 0, 0);
}

// ---------------- fused cast: transpose x,cx -> bf16 [b][n][c]; weights -> bf16 ----
// grid (144, NB, 2): x<128 -> 32-row transpose tile; x>=128 -> weight cast (m = z*2+y).
__global__ __launch_bounds__(256) void cast_all(
    const float* __restrict__ x, const float* __restrict__ cx,
    const float* __restrict__ Wq, const float* __restrict__ Wk,
    const float* __restrict__ Wv, const float* __restrict__ Wo,
    ushort* __restrict__ Xt, ushort* __restrict__ Ct, ushort* __restrict__ Wall)
{
    const int t = threadIdx.x;
    if (blockIdx.x >= 128) {
        const int sub = blockIdx.x - 128;                // 0..15
        const int m = blockIdx.z * 2 + blockIdx.y;       // 0..3
        const float* src = (m == 0) ? Wq : (m == 1) ? Wk : (m == 2) ? Wv : Wo;
        const int off = sub * 1024 + t * 4;
        const float4 v = *(const float4*)(src + off);
        ushort4 o;
        o.x = f2bf(v.x); o.y = f2bf(v.y); o.z = f2bf(v.z); o.w = f2bf(v.w);
        *(ushort4*)(Wall + m * 16384 + off) = o;
        return;
    }
    __shared__ ushort L[32][130];
    const int n0 = blockIdx.x * 32;
    const int b  = blockIdx.y;
    const float* in = (blockIdx.z == 0) ? x : cx;
    ushort* outp    = (blockIdx.z == 0) ? Xt : Ct;
    const int nl = t & 31, cq = t >> 5;          // 8 c-lanes
    #pragma unroll
    for (int cc = cq; cc < CD; cc += 8)
        L[nl][cc] = f2bf(in[((size_t)b * CD + cc) * NSP + n0 + nl]);
    __syncthreads();
    const int nr = t >> 3, cs = (t & 7) * 16;    // 32 rows x 16 c per thread
    unsigned u[8];
    #pragma unroll
    for (int w = 0; w < 8; ++w)
        u[w] = (unsigned)L[nr][cs + 2 * w] | ((unsigned)L[nr][cs + 2 * w + 1] << 16);
    ushort* dst = outp + ((size_t)(b * NSP + n0 + nr)) * CD + cs;
    *(uint4*)(dst)     = make_uint4(u[0], u[1], u[2], u[3]);
    *(uint4*)(dst + 8) = make_uint4(u[4], u[5], u[6], u[7]);
}

// ---------------- MFMA q,k,v projection + norm partials ----------------
__global__ __launch_bounds__(256) void proj_qkv_mfma(
    const ushort* __restrict__ Xt, const ushort* __restrict__ Ct,
    const ushort* __restrict__ Wall,
    const float* __restrict__ Bq, const float* __restrict__ Bk, const float* __restrict__ Bv,
    ushort* __restrict__ qh, ushort* __restrict__ kh, ushort* __restrict__ V16,
    float* __restrict__ partQ, float* __restrict__ partK)
{
    const int t = threadIdx.x;
    const int wid = t >> 6, lane = t & 63;
    const int g = lane >> 4, n16 = lane & 15;
    const int nt = blockIdx.x;
    const int b  = nt >> 8;
    const int xblk = nt & 255;
    const int nb = xblk * 16;
    const int o0 = (blockIdx.y * 4 + wid) * 16;

    const ushort* Wq = Wall;
    const ushort* Wk = Wall + 16384;
    const ushort* Wv = Wall + 32768;
    const size_t xrow = ((size_t)(b * NSP + nb + n16)) * CD;
    const size_t wrow = (size_t)(o0 + n16) * CD;

    f32x4 aq = {0,0,0,0}, ak = {0,0,0,0}, av = {0,0,0,0};
    #pragma unroll
    for (int ks = 0; ks < 4; ++ks) {
        const int k0 = ks * 32 + g * 8;
        const bf16x8 bx = *(const bf16x8*)(Xt + xrow + k0);
        const bf16x8 bc = *(const bf16x8*)(Ct + xrow + k0);
        const bf16x8 wqf = *(const bf16x8*)(Wq + wrow + k0);
        const bf16x8 wkf = *(const bf16x8*)(Wk + wrow + k0);
        const bf16x8 wvf = *(const bf16x8*)(Wv + wrow + k0);
        aq = __builtin_amdgcn_mfma_f32_16x16x32_bf16(wqf, bx, aq, 0, 0, 0);
        ak = __builtin_amdgcn_mfma_f32_16x16x32_bf16(wkf, bc, ak, 0, 0, 0);
        av = __builtin_amdgcn_mfma_f32_16x16x32_bf16(wvf, bc, av, 0, 0, 0);
    }
    float sq[4], sk[4];
    #pragma unroll
    for (int r = 0; r < 4; ++r) {
        const int o = o0 + 4 * g + r;
        const size_t row = ((size_t)(b * CD + o)) * NSP + nb + n16;
        const float qv = aq[r] + Bq[o];
        const float kv = ak[r] + Bk[o];
        qh[row]  = f2bf(qv);
        kh[row]  = f2bf(kv);
        V16[row] = f2bf(av[r] + Bv[o]);
        sq[r] = qv * qv; sk[r] = kv * kv;
    }
    #pragma unroll
    for (int r = 0; r < 4; ++r) {
        #pragma unroll
        for (int off = 1; off < 16; off <<= 1) {
            sq[r] += __shfl_xor(sq[r], off);
            sk[r] += __shfl_xor(sk[r], off);
        }
    }
    if (n16 == 0) {
        #pragma unroll
        for (int r = 0; r < 4; ++r) {
            const int ch = b * CD + o0 + 4 * g + r;
            partQ[(size_t)ch * 256 + xblk] = sq[r];
            partK[(size_t)ch * 256 + xblk] = sk[r];
        }
    }
}

// ---------------- reduce norm partials -> scales ----------------
__global__ __launch_bounds__(256) void normfin(
    const float* __restrict__ partQ, const float* __restrict__ partK,
    float* __restrict__ scq, float* __restrict__ sck)
{
    const int ch = blockIdx.x & 255, isK = blockIdx.x >> 8;
    const float* p = (isK ? partK : partQ) + (size_t)ch * 256;
    const int t = threadIdx.x;
    float v = p[t];
    #pragma unroll
    for (int off = 32; off > 0; off >>= 1) v += __shfl_down(v, off, 64);
    __shared__ float red[4];
    if ((t & 63) == 0) red[t >> 6] = v;
    __syncthreads();
    if (t == 0) {
        const float total = red[0] + red[1] + red[2] + red[3];
        const float sc = (isK ? 1.0f : QSCALE) / fmaxf(sqrtf(total), 1e-12f);
        (isK ? sck : scq)[ch] = sc;
    }
}

// ---------------- pack q,k -> bf16 chunk-major [bh][n/64][c=d/8][n%64][8] ----------------
// grid (16, 8, 4): z = c-chunk quad
__global__ __launch_bounds__(256) void pack_qk(
    const ushort* __restrict__ qh, const ushort* __restrict__ kh,
    const float* __restrict__ scq, const float* __restrict__ sck,
    ushort* __restrict__ Qt, ushort* __restrict__ Kt)
{
    const int n  = blockIdx.x * 256 + threadIdx.x;
    const int bh = blockIdx.y, cq = blockIdx.z;
    const int b = bh >> 2, h = bh & 3;
    unsigned qw[4], kw[4];
    #pragma unroll
    for (int e = 0; e < 4; ++e) {
        const int dp = cq * 4 + e;
        const int gr = b * CD + h * 32 + 2 * dp;
        const float fq0 = bf2f(qh[(size_t)gr * NSP + n]) * scq[gr];
        const float fq1 = bf2f(qh[(size_t)(gr + 1) * NSP + n]) * scq[gr + 1];
        const float fk0 = bf2f(kh[(size_t)gr * NSP + n]) * sck[gr];
        const float fk1 = bf2f(kh[(size_t)(gr + 1) * NSP + n]) * sck[gr + 1];
        qw[e] = pk2bf(fq0, fq1);
        kw[e] = pk2bf(fk0, fk1);
    }
    const int jb = n >> 6, jr = n & 63;
    const size_t base = ((size_t)(bh * (NSP / 64) + jb)) * 4 + cq;
    *(uint4*)(Qt + base * 512 + jr * 8) = make_uint4(qw[0], qw[1], qw[2], qw[3]);
    *(uint4*)(Kt + base * 512 + jr * 8) = make_uint4(kw[0], kw[1], kw[2], kw[3]);
}

// ---------------- MFMA flash attention partials ----------------
// grid 1024, 256 threads (4 waves, 32 q/wave). bh=f&7, it32=(f>>3)&31, js=f>>8.
// 4-buffer K/V rotation: raw s_barrier + counted vmcnt keeps 2 steps of
// global_load_lds prefetch in flight across barriers (no vmcnt(0) drain).
// K staged with source permute lane^(wid*2), read index ^(g*2): kills the
// 8-way read conflict (each g hits a distinct bank group).
__global__ __launch_bounds__(256, 4) void attn_mfma(
    const ushort* __restrict__ Qt, const ushort* __restrict__ Kt,
    const ushort* __restrict__ V16,
    unsigned* __restrict__ pacc, float* __restrict__ pl)
{
    __shared__ __align__(16) ushort Kl[4][2048];   // 16KB
    __shared__ __align__(16) ushort Vl[4][2048];   // 16KB

    const int t = threadIdx.x;
    const int wid = t >> 6, lane = t & 63;
    const int g = lane >> 4, n16 = lane & 15;
    const int f = blockIdx.x;
    const int bh = f & 7, it32 = (f >> 3) & 31, js = f >> 8;
    const int b = bh >> 2, h = bh & 3;
    const int i0 = it32 * 128 + wid * 32;

    const ushort* QtB = Qt + (size_t)bh * NSP * 32;
    const ushort* KtB = Kt + (size_t)bh * NSP * 32;
    const ushort* Vb  = V16 + (size_t)(b * CD + h * 32) * NSP;

    const size_t qoff = ((size_t)(i0 >> 6) * 4 + g) * 512 + (size_t)(i0 & 63) * 8;
    const bf16x8 qf0 = *(const bf16x8*)(QtB + qoff + n16 * 8);
    const bf16x8 qf1 = *(const bf16x8*)(QtB + qoff + (16 + n16) * 8);

    f32x4 acc00 = {0,0,0,0}, acc01 = {0,0,0,0}, acc10 = {0,0,0,0}, acc11 = {0,0,0,0};
    float l0 = 0.f, l1 = 0.f;
    const f32x4 zero = {0,0,0,0};

    const int klp = lane ^ (wid * 2);               // K source permute
    const int vd  = wid * 8 + (lane >> 3);          // V row this lane stages
    const int vsw = (lane & 7) ^ (lane >> 3);       // V 16B-chunk XOR swizzle
    auto stageK = [&](int buf, int jt) {
        gload_lds16(KtB + ((size_t)(jt >> 6) * 4 + wid) * 512 + klp * 8,
                    &Kl[buf][wid * 512]);
    };
    auto stageV = [&](int buf, int jt) {
        gload_lds16(Vb + (size_t)vd * NSP + jt + vsw * 8, &Vl[buf][wid * 512]);
    };

    const int jbeg = js * (NSP / JS);
    stageK(0, jbeg);          stageV(0, jbeg);
    stageK(1, jbeg + JSTEP);  stageV(1, jbeg + JSTEP);

    for (int step = 0; step < NSTEP; ++step) {
        const int jt = jbeg + step * JSTEP;
        if (step + 2 < NSTEP) {
            stageK((step + 2) & 3, jt + 2 * JSTEP);
            stageV((step + 2) & 3, jt + 2 * JSTEP);
            asm volatile("s_waitcnt vmcnt(4)" ::: "memory");   // drain this step's loads
        } else if (step + 1 < NSTEP) {
            asm volatile("s_waitcnt vmcnt(2)" ::: "memory");
        } else {
            asm volatile("s_waitcnt vmcnt(0)" ::: "memory");
        }
        __builtin_amdgcn_s_barrier();
        const int cur = step & 3;

        #pragma unroll
        for (int s = 0; s < 2; ++s) {
            const bf16x8 kf0 = *(const bf16x8*)(&Kl[cur][g * 512 + ((s * 32 + n16) ^ (g * 2)) * 8]);
            const bf16x8 kf1 = *(const bf16x8*)(&Kl[cur][g * 512 + ((s * 32 + 16 + n16) ^ (g * 2)) * 8]);
            const int c0 = ((4 * s + (g >> 1)) ^ (n16 & 7)) * 8 + (g & 1) * 4;
            const int c1 = ((4 * s + 2 + (g >> 1)) ^ (n16 & 7)) * 8 + (g & 1) * 4;
            union { uint2 u2[2]; bf16x8 v; } v0, v1;
            v0.u2[0] = *(const uint2*)(&Vl[cur][n16 * 64 + c0]);
            v0.u2[1] = *(const uint2*)(&Vl[cur][n16 * 64 + c1]);
            v1.u2[0] = *(const uint2*)(&Vl[cur][(16 + n16) * 64 + c0]);
            v1.u2[1] = *(const uint2*)(&Vl[cur][(16 + n16) * 64 + c1]);

            #pragma unroll
            for (int it = 0; it < 2; ++it) {
                const bf16x8 qf = it ? qf1 : qf0;
                f32x4 s0 = __builtin_amdgcn_mfma_f32_16x16x32_bf16(kf0, qf, zero, 0, 0, 0);
                f32x4 s1 = __builtin_amdgcn_mfma_f32_16x16x32_bf16(kf1, qf, zero, 0, 0, 0);
                const float p0 = __builtin_amdgcn_exp2f(s0.x);
                const float p1 = __builtin_amdgcn_exp2f(s0.y);
                const float p2 = __builtin_amdgcn_exp2f(s0.z);
                const float p3 = __builtin_amdgcn_exp2f(s0.w);
                const float p4 = __builtin_amdgcn_exp2f(s1.x);
                const float p5 = __builtin_amdgcn_exp2f(s1.y);
                const float p6 = __builtin_amdgcn_exp2f(s1.z);
                const float p7 = __builtin_amdgcn_exp2f(s1.w);
                const float ps = ((p0 + p1) + (p2 + p3)) + ((p4 + p5) + (p6 + p7));
                if (it) l1 += ps; else l0 += ps;
                union { unsigned u[4]; bf16x8 v; } pf;
                pf.u[0] = pk2bf(p0, p1);
                pf.u[1] = pk2bf(p2, p3);
                pf.u[2] = pk2bf(p4, p5);
                pf.u[3] = pk2bf(p6, p7);
                if (it) {
                    acc10 = __builtin_amdgcn_mfma_f32_16x16x32_bf16(v0.v, pf.v, acc10, 0, 0, 0);
                    acc11 = __builtin_amdgcn_mfma_f32_16x16x32_bf16(v1.v, pf.v, acc11, 0, 0, 0);
                } else {
                    acc00 = __builtin_amdgcn_mfma_f32_16x16x32_bf16(v0.v, pf.v, acc00, 0, 0, 0);
                    acc01 = __builtin_amdgcn_mfma_f32_16x16x32_bf16(v1.v, pf.v, acc01, 0, 0, 0);
                }
            }
        }
    }

    l0 += __shfl_xor(l0, 16); l0 += __shfl_xor(l0, 32);
    l1 += __shfl_xor(l1, 16); l1 += __shfl_xor(l1, 32);

    const size_t base = (size_t)js * 8 + bh;
    if (lane < 16) {
        pl[base * NSP + i0 + n16]      = l0;
        pl[base * NSP + i0 + 16 + n16] = l1;
    }
    unsigned* pb = pacc + base * 16 * NSP;
    const int col0 = i0 + n16, col1 = i0 + 16 + n16;
    pb[(size_t)(2 * g)     * NSP + col0] = pk2bf(acc00[0], acc00[1]);
    pb[(size_t)(2 * g + 1) * NSP + col0] = pk2bf(acc00[2], acc00[3]);
    pb[(size_t)(8 + 2 * g)     * NSP + col0] = pk2bf(acc01[0], acc01[1]);
    pb[(size_t)(8 + 2 * g + 1) * NSP + col0] = pk2bf(acc01[2], acc01[3]);
    pb[(size_t)(2 * g)     * NSP + col1] = pk2bf(acc10[0], acc10[1]);
    pb[(size_t)(2 * g + 1) * NSP + col1] = pk2bf(acc10[2], acc10[3]);
    pb[(size_t)(8 + 2 * g)     * NSP + col1] = pk2bf(acc11[0], acc11[1]);
    pb[(size_t)(8 + 2 * g + 1) * NSP + col1] = pk2bf(acc11[2], acc11[3]);
}

// ---------------- combine partials -> Yt bf16 [b][n][c] ----------------
// grid (16, 8, 4): z = d-chunk
__global__ __launch_bounds__(256) void combine_kernel(
    const unsigned* __restrict__ pacc, const float* __restrict__ pl,
    ushort* __restrict__ Yt)
{
    const int i  = blockIdx.x * 256 + threadIdx.x;
    const int bh = blockIdx.y, z = blockIdx.z;
    const int b = bh >> 2, h = bh & 3;
    float L = 0.f;
    #pragma unroll
    for (int s = 0; s < JS; ++s) L += pl[((size_t)(s * 8 + bh)) * NSP + i];
    const float invL = 1.0f / L;
    unsigned u[4];
    #pragma unroll
    for (int e = 0; e < 4; ++e) {
        const int dp = z * 4 + e;
        float a0 = 0.f, a1 = 0.f;
        #pragma unroll
        for (int s = 0; s < JS; ++s) {
            const unsigned w = pacc[(((size_t)(s * 8 + bh)) * 16 + dp) * NSP + i];
            union { unsigned u; float f; } lo, hi;
            lo.u = w << 16; hi.u = w & 0xffff0000u;
            a0 += lo.f; a1 += hi.f;
        }
        u[e] = pk2bf(a0 * invL, a1 * invL);
    }
    ushort* dst = Yt + ((size_t)(b * NSP + i)) * CD + h * 32 + z * 8;
    *(uint4*)(dst) = make_uint4(u[0], u[1], u[2], u[3]);
}

// ---------------- MFMA output projection ----------------
__global__ __launch_bounds__(256) void proj_out_mfma(
    const ushort* __restrict__ Yt, const ushort* __restrict__ Wall,
    const float* __restrict__ Bo, float* __restrict__ outp)
{
    const int t = threadIdx.x;
    const int wid = t >> 6, lane = t & 63;
    const int g = lane >> 4, n16 = lane & 15;
    const int nt = blockIdx.x;
    const int b  = nt >> 8;
    const int nb = (nt & 255) * 16;
    const int o0 = (blockIdx.y * 4 + wid) * 16;

    const ushort* Wo = Wall + 49152;
    const size_t xrow = ((size_t)(b * NSP + nb + n16)) * CD;
    const size_t wrow = (size_t)(o0 + n16) * CD;

    f32x4 a = {0,0,0,0};
    #pragma unroll
    for (int ks = 0; ks < 4; ++ks) {
        const int k0 = ks * 32 + g * 8;
        const bf16x8 bx = *(const bf16x8*)(Yt + xrow + k0);
        const bf16x8 wf = *(const bf16x8*)(Wo + wrow + k0);
        a = __builtin_amdgcn_mfma_f32_16x16x32_bf16(wf, bx, a, 0, 0, 0);
    }
    #pragma unroll
    for (int r = 0; r < 4; ++r) {
        const int o = o0 + 4 * g + r;
        outp[((size_t)(b * CD + o)) * NSP + nb + n16] = a[r] + Bo[o];
    }
}

extern "C" void kernel_launch(void* const* d_in, const int* in_sizes, int n_in,
                              void* d_out, int out_size, void* d_ws, size_t ws_size,
                              hipStream_t stream)
{
    const float* x  = (const float*)d_in[0];
    const float* cx = (const float*)d_in[1];
    const float* Wq = (const float*)d_in[2];
    const float* bq = (const float*)d_in[3];
    const float* Wk = (const float*)d_in[4];
    const float* bk = (const float*)d_in[5];
    const float* Wv = (const float*)d_in[6];
    const float* bv = (const float*)d_in[7];
    const float* Wo = (const float*)d_in[8];
    const float* bo = (const float*)d_in[9];
    float* out = (float*)d_out;

    char* w = (char*)d_ws;
    ushort*  qh   = (ushort*)w;  w += (size_t)NB * CD * NSP * 2;        // 2 MB
    ushort*  kh   = (ushort*)w;  w += (size_t)NB * CD * NSP * 2;        // 2 MB
    float*   scq  = (float*)w;   w += 1024;
    float*   sck  = (float*)w;   w += 1024;
    float*   partQ = (float*)w;  w += (size_t)NB * CD * 256 * 4;        // 256 KB
    float*   partK = (float*)w;  w += (size_t)NB * CD * 256 * 4;        // 256 KB
    ushort*  Qt   = (ushort*)w;  w += (size_t)NB * NH * NSP * 32 * 2;   // 2 MB
    ushort*  Kt   = (ushort*)w;  w += (size_t)NB * NH * NSP * 32 * 2;   // 2 MB
    ushort*  V16  = (ushort*)w;  w += (size_t)NB * CD * NSP * 2;        // 2 MB
    unsigned* pacc = (unsigned*)w; w += (size_t)JS * 8 * 16 * NSP * 4;  // 8 MB
    float*   pl   = (float*)w;   w += (size_t)JS * 8 * NSP * 4;         // 512 KB
    ushort*  Xt   = (ushort*)w;  w += (size_t)NB * NSP * CD * 2;        // 2 MB
    ushort*  Ct   = (ushort*)w;  w += (size_t)NB * NSP * CD * 2;        // 2 MB
    ushort*  Yt   = (ushort*)w;  w += (size_t)NB * NSP * CD * 2;        // 2 MB
    ushort*  Wall = (ushort*)w;                                         // 128 KB

    cast_all<<<dim3(144, NB, 2), 256, 0, stream>>>(x, cx, Wq, Wk, Wv, Wo, Xt, Ct, Wall);
    proj_qkv_mfma<<<dim3(512, 2), 256, 0, stream>>>(Xt, Ct, Wall, bq, bk, bv,
                                                    qh, kh, V16, partQ, partK);
    normfin<<<dim3(512), 256, 0, stream>>>(partQ, partK, scq, sck);
    pack_qk<<<dim3(16, 8, 4), 256, 0, stream>>>(qh, kh, scq, sck, Qt, Kt);
    attn_mfma<<<dim3(1024), 256, 0, stream>>>(Qt, Kt, V16, pacc, pl);
    combine_kernel<<<dim3(16, 8, 4), 256, 0, stream>>>(pacc, pl, Yt);
    proj_out_mfma<<<dim3(512, 2), 256, 0, stream>>>(Yt, Wall, bo, out);
}

// Round 11
// 65.977 us; speedup vs baseline: 2.4212x; 1.1050x over previous
//
#include <hip/hip_runtime.h>
#include <hip/hip_bf16.h>
#include <math.h>

#define NSP 4096      // h*w*z = 16^3
#define CD 128        // channels
#define NB 2          // batch
#define NH 4          // heads
#define JS 4          // j-splits in attention
#define JSTEP 64
#define NSTEP ((NSP / JS) / JSTEP)   // 16

typedef __attribute__((ext_vector_type(8))) short bf16x8;   // 8 bf16 (4 VGPRs)
typedef __attribute__((ext_vector_type(4))) float f32x4;

static constexpr float QSCALE = 10.0f * 1.4426950408889634f;  // scale * log2(e)

__device__ __forceinline__ ushort f2bf(float f) {
    union { float f; unsigned u; } v; v.f = f;
    unsigned r = v.u + 0x7fffu + ((v.u >> 16) & 1u);   // RNE, finite inputs only
    return (ushort)(r >> 16);
}
__device__ __forceinline__ float bf2f(ushort u) {
    union { unsigned u; float f; } v; v.u = ((unsigned)u) << 16;
    return v.f;
}
// RNE pack via compiler builtin (v_cvt_pk_bf16_f32): low16=a, high16=b
__device__ __forceinline__ unsigned pk2bf(float a, float b) {
    union { __hip_bfloat162 h; unsigned u; } t;
    t.h = __float22bfloat162_rn(make_float2(a, b));
    return t.u;
}
__device__ __forceinline__ void gload_lds16(const void* g, void* l) {
    __builtin_amdgcn_global_load_lds(
        (const __attribute__((address_space(1))) unsigned int*)g,
        (__attribute__((address_space(3))) unsigned int*)l, 16, 0, 0);
}

// ---------------- fused cast: transpose x,cx -> bf16 [b][n][c]; weights -> bf16 ----
__global__ __launch_bounds__(256) void cast_all(
    const float* __restrict__ x, const float* __restrict__ cx,
    const float* __restrict__ Wq, const float* __restrict__ Wk,
    const float* __restrict__ Wv, const float* __restrict__ Wo,
    ushort* __restrict__ Xt, ushort* __restrict__ Ct, ushort* __restrict__ Wall)
{
    const int t = threadIdx.x;
    if (blockIdx.x >= 128) {
        const int sub = blockIdx.x - 128;                // 0..15
        const int m = blockIdx.z * 2 + blockIdx.y;       // 0..3
        const float* src = (m == 0) ? Wq : (m == 1) ? Wk : (m == 2) ? Wv : Wo;
        const int off = sub * 1024 + t * 4;
        const float4 v = *(const float4*)(src + off);
        ushort4 o;
        o.x = f2bf(v.x); o.y = f2bf(v.y); o.z = f2bf(v.z); o.w = f2bf(v.w);
        *(ushort4*)(Wall + m * 16384 + off) = o;
        return;
    }
    __shared__ ushort L[32][130];
    const int n0 = blockIdx.x * 32;
    const int b  = blockIdx.y;
    const float* in = (blockIdx.z == 0) ? x : cx;
    ushort* outp    = (blockIdx.z == 0) ? Xt : Ct;
    const int nl = t & 31, cq = t >> 5;
    #pragma unroll
    for (int cc = cq; cc < CD; cc += 8)
        L[nl][cc] = f2bf(in[((size_t)b * CD + cc) * NSP + n0 + nl]);
    __syncthreads();
    const int nr = t >> 3, cs = (t & 7) * 16;
    unsigned u[8];
    #pragma unroll
    for (int w = 0; w < 8; ++w)
        u[w] = (unsigned)L[nr][cs + 2 * w] | ((unsigned)L[nr][cs + 2 * w + 1] << 16);
    ushort* dst = outp + ((size_t)(b * NSP + n0 + nr)) * CD + cs;
    *(uint4*)(dst)     = make_uint4(u[0], u[1], u[2], u[3]);
    *(uint4*)(dst + 8) = make_uint4(u[4], u[5], u[6], u[7]);
}

// ---------------- MFMA q,k,v projection: Qt/Kt chunk-major RAW + V16 + norm partials --
// Qt/Kt layout: [bh][n/64][d/8][n%64][8] (raw, unscaled bf16)
__global__ __launch_bounds__(256) void proj_qkv_mfma(
    const ushort* __restrict__ Xt, const ushort* __restrict__ Ct,
    const ushort* __restrict__ Wall,
    const float* __restrict__ Bq, const float* __restrict__ Bk, const float* __restrict__ Bv,
    ushort* __restrict__ Qt, ushort* __restrict__ Kt, ushort* __restrict__ V16,
    float* __restrict__ partQ, float* __restrict__ partK)
{
    const int t = threadIdx.x;
    const int wid = t >> 6, lane = t & 63;
    const int g = lane >> 4, n16 = lane & 15;
    const int nt = blockIdx.x;
    const int b  = nt >> 8;
    const int xblk = nt & 255;
    const int nb = xblk * 16;
    const int o0 = (blockIdx.y * 4 + wid) * 16;

    const ushort* Wq = Wall;
    const ushort* Wk = Wall + 16384;
    const ushort* Wv = Wall + 32768;
    const size_t xrow = ((size_t)(b * NSP + nb + n16)) * CD;
    const size_t wrow = (size_t)(o0 + n16) * CD;

    f32x4 aq = {0,0,0,0}, ak = {0,0,0,0}, av = {0,0,0,0};
    #pragma unroll
    for (int ks = 0; ks < 4; ++ks) {
        const int k0 = ks * 32 + g * 8;
        const bf16x8 bx = *(const bf16x8*)(Xt + xrow + k0);
        const bf16x8 bc = *(const bf16x8*)(Ct + xrow + k0);
        const bf16x8 wqf = *(const bf16x8*)(Wq + wrow + k0);
        const bf16x8 wkf = *(const bf16x8*)(Wk + wrow + k0);
        const bf16x8 wvf = *(const bf16x8*)(Wv + wrow + k0);
        aq = __builtin_amdgcn_mfma_f32_16x16x32_bf16(wqf, bx, aq, 0, 0, 0);
        ak = __builtin_amdgcn_mfma_f32_16x16x32_bf16(wkf, bc, ak, 0, 0, 0);
        av = __builtin_amdgcn_mfma_f32_16x16x32_bf16(wvf, bc, av, 0, 0, 0);
    }
    const int jb = nb >> 6, jr = (nb & 63) + n16;
    float sq[4], sk[4];
    #pragma unroll
    for (int r = 0; r < 4; ++r) {
        const int o = o0 + 4 * g + r;
        const float qv = aq[r] + Bq[o];
        const float kv = ak[r] + Bk[o];
        V16[((size_t)(b * CD + o)) * NSP + nb + n16] = f2bf(av[r] + Bv[o]);
        const int bh = b * NH + (o >> 5);
        const size_t idx = (((size_t)(bh * 64 + jb)) * 4 + ((o & 31) >> 3)) * 512
                         + jr * 8 + (o & 7);
        Qt[idx] = f2bf(qv);
        Kt[idx] = f2bf(kv);
        sq[r] = qv * qv; sk[r] = kv * kv;
    }
    #pragma unroll
    for (int r = 0; r < 4; ++r) {
        #pragma unroll
        for (int off = 1; off < 16; off <<= 1) {
            sq[r] += __shfl_xor(sq[r], off);
            sk[r] += __shfl_xor(sk[r], off);
        }
    }
    if (n16 == 0) {
        #pragma unroll
        for (int r = 0; r < 4; ++r) {
            const int ch = b * CD + o0 + 4 * g + r;
            partQ[(size_t)ch * 256 + xblk] = sq[r];
            partK[(size_t)ch * 256 + xblk] = sk[r];
        }
    }
}

// ---------------- reduce norm partials -> combined per-channel factor ----------------
// fsc[ch] = QSCALE / (max(||q_ch||,eps) * max(||k_ch||,eps)); grid 256 (one per ch)
__global__ __launch_bounds__(256) void normfin(
    const float* __restrict__ partQ, const float* __restrict__ partK,
    float* __restrict__ fsc)
{
    const int ch = blockIdx.x;
    const int t = threadIdx.x;
    float vq = partQ[(size_t)ch * 256 + t];
    float vk = partK[(size_t)ch * 256 + t];
    #pragma unroll
    for (int off = 32; off > 0; off >>= 1) {
        vq += __shfl_down(vq, off, 64);
        vk += __shfl_down(vk, off, 64);
    }
    __shared__ float redq[4], redk[4];
    if ((t & 63) == 0) { redq[t >> 6] = vq; redk[t >> 6] = vk; }
    __syncthreads();
    if (t == 0) {
        const float nq = sqrtf(redq[0] + redq[1] + redq[2] + redq[3]);
        const float nk = sqrtf(redk[0] + redk[1] + redk[2] + redk[3]);
        fsc[ch] = QSCALE / (fmaxf(nq, 1e-12f) * fmaxf(nk, 1e-12f));
    }
}

// ---------------- MFMA flash attention partials ----------------
// grid 1024, 4 waves, 32 q/wave. Q raw from Qt, combined scale fsc applied in-register.
// 4-buffer K/V rotation, raw s_barrier + counted vmcnt (2 steps of prefetch in flight).
__global__ __launch_bounds__(256, 4) void attn_mfma(
    const ushort* __restrict__ Qt, const ushort* __restrict__ Kt,
    const ushort* __restrict__ V16, const float* __restrict__ fsc,
    unsigned* __restrict__ pacc, float* __restrict__ pl)
{
    __shared__ __align__(16) ushort Kl[4][2048];   // 16KB
    __shared__ __align__(16) ushort Vl[4][2048];   // 16KB

    const int t = threadIdx.x;
    const int wid = t >> 6, lane = t & 63;
    const int g = lane >> 4, n16 = lane & 15;
    const int f = blockIdx.x;
    const int bh = f & 7, it32 = (f >> 3) & 31, js = f >> 8;
    const int b = bh >> 2, h = bh & 3;
    const int i0 = it32 * 128 + wid * 32;

    const ushort* QtB = Qt + (size_t)bh * NSP * 32;
    const ushort* KtB = Kt + (size_t)bh * NSP * 32;
    const ushort* Vb  = V16 + (size_t)(b * CD + h * 32) * NSP;

    // combined per-d scale for this lane's 8 d's (d = g*8+e)
    const float* fb = fsc + b * CD + h * 32 + g * 8;
    const f32x4 fA = *(const f32x4*)(fb);
    const f32x4 fB = *(const f32x4*)(fb + 4);

    const size_t qoff = ((size_t)(i0 >> 6) * 4 + g) * 512 + (size_t)(i0 & 63) * 8;
    const bf16x8 qr0 = *(const bf16x8*)(QtB + qoff + n16 * 8);
    const bf16x8 qr1 = *(const bf16x8*)(QtB + qoff + (16 + n16) * 8);
    auto scaleq = [&](bf16x8 q) -> bf16x8 {
        union { unsigned u[4]; bf16x8 v; } o;
        o.u[0] = pk2bf(bf2f((ushort)q[0]) * fA.x, bf2f((ushort)q[1]) * fA.y);
        o.u[1] = pk2bf(bf2f((ushort)q[2]) * fA.z, bf2f((ushort)q[3]) * fA.w);
        o.u[2] = pk2bf(bf2f((ushort)q[4]) * fB.x, bf2f((ushort)q[5]) * fB.y);
        o.u[3] = pk2bf(bf2f((ushort)q[6]) * fB.z, bf2f((ushort)q[7]) * fB.w);
        return o.v;
    };
    const bf16x8 qf0 = scaleq(qr0);
    const bf16x8 qf1 = scaleq(qr1);

    f32x4 acc00 = {0,0,0,0}, acc01 = {0,0,0,0}, acc10 = {0,0,0,0}, acc11 = {0,0,0,0};
    float l0 = 0.f, l1 = 0.f;
    const f32x4 zero = {0,0,0,0};

    const int klp = lane ^ (wid * 2);               // K source permute
    const int vd  = wid * 8 + (lane >> 3);          // V row this lane stages
    const int vsw = (lane & 7) ^ (lane >> 3);       // V 16B-chunk XOR swizzle
    auto stageK = [&](int buf, int jt) {
        gload_lds16(KtB + ((size_t)(jt >> 6) * 4 + wid) * 512 + klp * 8,
                    &Kl[buf][wid * 512]);
    };
    auto stageV = [&](int buf, int jt) {
        gload_lds16(Vb + (size_t)vd * NSP + jt + vsw * 8, &Vl[buf][wid * 512]);
    };

    const int jbeg = js * (NSP / JS);
    stageK(0, jbeg);          stageV(0, jbeg);
    stageK(1, jbeg + JSTEP);  stageV(1, jbeg + JSTEP);

    for (int step = 0; step < NSTEP; ++step) {
        const int jt = jbeg + step * JSTEP;
        if (step + 2 < NSTEP) {
            stageK((step + 2) & 3, jt + 2 * JSTEP);
            stageV((step + 2) & 3, jt + 2 * JSTEP);
            asm volatile("s_waitcnt vmcnt(4)" ::: "memory");
        } else if (step + 1 < NSTEP) {
            asm volatile("s_waitcnt vmcnt(2)" ::: "memory");
        } else {
            asm volatile("s_waitcnt vmcnt(0)" ::: "memory");
        }
        __builtin_amdgcn_s_barrier();
        const int cur = step & 3;

        #pragma unroll
        for (int s = 0; s < 2; ++s) {
            const bf16x8 kf0 = *(const bf16x8*)(&Kl[cur][g * 512 + ((s * 32 + n16) ^ (g * 2)) * 8]);
            const bf16x8 kf1 = *(const bf16x8*)(&Kl[cur][g * 512 + ((s * 32 + 16 + n16) ^ (g * 2)) * 8]);
            const int c0 = ((4 * s + (g >> 1)) ^ (n16 & 7)) * 8 + (g & 1) * 4;
            const int c1 = ((4 * s + 2 + (g >> 1)) ^ (n16 & 7)) * 8 + (g & 1) * 4;
            union { uint2 u2[2]; bf16x8 v; } v0, v1;
            v0.u2[0] = *(const uint2*)(&Vl[cur][n16 * 64 + c0]);
            v0.u2[1] = *(const uint2*)(&Vl[cur][n16 * 64 + c1]);
            v1.u2[0] = *(const uint2*)(&Vl[cur][(16 + n16) * 64 + c0]);
            v1.u2[1] = *(const uint2*)(&Vl[cur][(16 + n16) * 64 + c1]);

            #pragma unroll
            for (int it = 0; it < 2; ++it) {
                const bf16x8 qf = it ? qf1 : qf0;
                f32x4 s0 = __builtin_amdgcn_mfma_f32_16x16x32_bf16(kf0, qf, zero, 0, 0, 0);
                f32x4 s1 = __builtin_amdgcn_mfma_f32_16x16x32_bf16(kf1, qf, zero, 0, 0, 0);
                const float p0 = __builtin_amdgcn_exp2f(s0.x);
                const float p1 = __builtin_amdgcn_exp2f(s0.y);
                const float p2 = __builtin_amdgcn_exp2f(s0.z);
                const float p3 = __builtin_amdgcn_exp2f(s0.w);
                const float p4 = __builtin_amdgcn_exp2f(s1.x);
                const float p5 = __builtin_amdgcn_exp2f(s1.y);
                const float p6 = __builtin_amdgcn_exp2f(s1.z);
                const float p7 = __builtin_amdgcn_exp2f(s1.w);
                const float ps = ((p0 + p1) + (p2 + p3)) + ((p4 + p5) + (p6 + p7));
                if (it) l1 += ps; else l0 += ps;
                union { unsigned u[4]; bf16x8 v; } pf;
                pf.u[0] = pk2bf(p0, p1);
                pf.u[1] = pk2bf(p2, p3);
                pf.u[2] = pk2bf(p4, p5);
                pf.u[3] = pk2bf(p6, p7);
                if (it) {
                    acc10 = __builtin_amdgcn_mfma_f32_16x16x32_bf16(v0.v, pf.v, acc10, 0, 0, 0);
                    acc11 = __builtin_amdgcn_mfma_f32_16x16x32_bf16(v1.v, pf.v, acc11, 0, 0, 0);
                } else {
                    acc00 = __builtin_amdgcn_mfma_f32_16x16x32_bf16(v0.v, pf.v, acc00, 0, 0, 0);
                    acc01 = __builtin_amdgcn_mfma_f32_16x16x32_bf16(v1.v, pf.v, acc01, 0, 0, 0);
                }
            }
        }
    }

    l0 += __shfl_xor(l0, 16); l0 += __shfl_xor(l0, 32);
    l1 += __shfl_xor(l1, 16); l1 += __shfl_xor(l1, 32);

    const size_t base = (size_t)js * 8 + bh;
    if (lane < 16) {
        pl[base * NSP + i0 + n16]      = l0;
        pl[base * NSP + i0 + 16 + n16] = l1;
    }
    unsigned* pb = pacc + base * 16 * NSP;
    const int col0 = i0 + n16, col1 = i0 + 16 + n16;
    pb[(size_t)(2 * g)     * NSP + col0] = pk2bf(acc00[0], acc00[1]);
    pb[(size_t)(2 * g + 1) * NSP + col0] = pk2bf(acc00[2], acc00[3]);
    pb[(size_t)(8 + 2 * g)     * NSP + col0] = pk2bf(acc01[0], acc01[1]);
    pb[(size_t)(8 + 2 * g + 1) * NSP + col0] = pk2bf(acc01[2], acc01[3]);
    pb[(size_t)(2 * g)     * NSP + col1] = pk2bf(acc10[0], acc10[1]);
    pb[(size_t)(2 * g + 1) * NSP + col1] = pk2bf(acc10[2], acc10[3]);
    pb[(size_t)(8 + 2 * g)     * NSP + col1] = pk2bf(acc11[0], acc11[1]);
    pb[(size_t)(8 + 2 * g + 1) * NSP + col1] = pk2bf(acc11[2], acc11[3]);
}

// ---------------- fused combine + output projection ----------------
// grid 512 blocks (b*256 + xblk), 256 threads (4 waves). Per block: 16 n, all 128 o.
// Phase 1: combine js-partials into LDS Y tile [16 n][128 c] bf16, XOR-swizzled chunks.
// Phase 2: MFMA with Wo (A=Wo rows, B=Y rows), write out fp32 [b][c][n].
__global__ __launch_bounds__(256) void combine_proj_out(
    const unsigned* __restrict__ pacc, const float* __restrict__ pl,
    const ushort* __restrict__ Wall, const float* __restrict__ Bo,
    float* __restrict__ outp)
{
    __shared__ __align__(16) ushort Yl[16][128];
    const int t = threadIdx.x;
    const int nt = blockIdx.x;
    const int b  = nt >> 8;
    const int nb = (nt & 255) * 16;

    // phase 1: tid -> (q = tid>>6, hh = (tid>>4)&3, nl = tid&15)
    {
        const int nl = t & 15, hh = (t >> 4) & 3, q = t >> 6;
        const int bh = b * NH + hh;
        const int n = nb + nl;
        float L = 0.f;
        #pragma unroll
        for (int s = 0; s < JS; ++s) L += pl[((size_t)(s * 8 + bh)) * NSP + n];
        const float invL = 1.0f / L;
        unsigned u[4];
        #pragma unroll
        for (int e = 0; e < 4; ++e) {
            const int dp = q * 4 + e;
            float a0 = 0.f, a1 = 0.f;
            #pragma unroll
            for (int s = 0; s < JS; ++s) {
                const unsigned w = pacc[(((size_t)(s * 8 + bh)) * 16 + dp) * NSP + n];
                union { unsigned u; float f; } lo, hi;
                lo.u = w << 16; hi.u = w & 0xffff0000u;
                a0 += lo.f; a1 += hi.f;
            }
            u[e] = pk2bf(a0 * invL, a1 * invL);
        }
        const int chunk = hh * 4 + q;                       // c = chunk*8 .. +7
        *(uint4*)(&Yl[nl][((chunk ^ (nl & 7)) * 8)]) = make_uint4(u[0], u[1], u[2], u[3]);
    }
    __syncthreads();

    // phase 2: wave wid -> o-tiles o0 = wid*16 and 64+wid*16
    const int wid = t >> 6, lane = t & 63;
    const int g = lane >> 4, n16 = lane & 15;
    const ushort* Wo = Wall + 49152;
    #pragma unroll
    for (int half = 0; half < 2; ++half) {
        const int o0 = half * 64 + wid * 16;
        const size_t wrow = (size_t)(o0 + n16) * CD;
        f32x4 a = {0,0,0,0};
        #pragma unroll
        for (int ks = 0; ks < 4; ++ks) {
            const bf16x8 wf = *(const bf16x8*)(Wo + wrow + ks * 32 + g * 8);
            const int chunk = ks * 4 + g;
            const bf16x8 yf = *(const bf16x8*)(&Yl[n16][((chunk ^ (n16 & 7)) * 8)]);
            a = __builtin_amdgcn_mfma_f32_16x16x32_bf16(wf, yf, a, 0, 0, 0);
        }
        #pragma unroll
        for (int r = 0; r < 4; ++r) {
            const int o = o0 + 4 * g + r;
            outp[((size_t)(b * CD + o)) * NSP + nb + n16] = a[r] + Bo[o];
        }
    }
}

extern "C" void kernel_launch(void* const* d_in, const int* in_sizes, int n_in,
                              void* d_out, int out_size, void* d_ws, size_t ws_size,
                              hipStream_t stream)
{
    const float* x  = (const float*)d_in[0];
    const float* cx = (const float*)d_in[1];
    const float* Wq = (const float*)d_in[2];
    const float* bq = (const float*)d_in[3];
    const float* Wk = (const float*)d_in[4];
    const float* bk = (const float*)d_in[5];
    const float* Wv = (const float*)d_in[6];
    const float* bv = (const float*)d_in[7];
    const float* Wo = (const float*)d_in[8];
    const float* bo = (const float*)d_in[9];
    float* out = (float*)d_out;

    char* w = (char*)d_ws;
    float*   fsc  = (float*)w;   w += 4096;
    float*   partQ = (float*)w;  w += (size_t)NB * CD * 256 * 4;        // 256 KB
    float*   partK = (float*)w;  w += (size_t)NB * CD * 256 * 4;        // 256 KB
    ushort*  Qt   = (ushort*)w;  w += (size_t)NB * NH * NSP * 32 * 2;   // 2 MB
    ushort*  Kt   = (ushort*)w;  w += (size_t)NB * NH * NSP * 32 * 2;   // 2 MB
    ushort*  V16  = (ushort*)w;  w += (size_t)NB * CD * NSP * 2;        // 2 MB
    unsigned* pacc = (unsigned*)w; w += (size_t)JS * 8 * 16 * NSP * 4;  // 8 MB
    float*   pl   = (float*)w;   w += (size_t)JS * 8 * NSP * 4;         // 512 KB
    ushort*  Xt   = (ushort*)w;  w += (size_t)NB * NSP * CD * 2;        // 2 MB
    ushort*  Ct   = (ushort*)w;  w += (size_t)NB * NSP * CD * 2;        // 2 MB
    ushort*  Wall = (ushort*)w;                                         // 128 KB

    cast_all<<<dim3(144, NB, 2), 256, 0, stream>>>(x, cx, Wq, Wk, Wv, Wo, Xt, Ct, Wall);
    proj_qkv_mfma<<<dim3(512, 2), 256, 0, stream>>>(Xt, Ct, Wall, bq, bk, bv,
                                                    Qt, Kt, V16, partQ, partK);
    normfin<<<dim3(256), 256, 0, stream>>>(partQ, partK, fsc);
    attn_mfma<<<dim3(1024), 256, 0, stream>>>(Qt, Kt, V16, fsc, pacc, pl);
    combine_proj_out<<<dim3(512), 256, 0, stream>>>(pacc, pl, Wall, bo, out);
}